// Round 6
// baseline (502.548 us; speedup 1.0000x reference)
//
#include <hip/hip_runtime.h>
#include <math.h>

#define N_NODES  100000
#define N_EDGES  1600000
#define IN_F     128
#define HID      64
#define HEADS    4
#define NCLS     16
#define D1       (HEADS*HID)    // 256
#define D2       (HEADS*NCLS)   // 64

#define SCAN_CHUNK 1024
#define SCAN_NB    ((N_NODES + SCAN_CHUNK - 1) / SCAN_CHUNK)   // 98
#define N_NODES_PAD (SCAN_NB * SCAN_CHUNK)                     // 100352
#define RB1 128        // reduce-stage-1 blocks
#define AGG_BLOCKS 2048   // persistent agg grid: 256 CU x 8 blocks/CU
#define AGG_WAVES  (AGG_BLOCKS * 4)
#define GEMM1_BLOCKS ((N_NODES + 63) / 64)            // 1563
#define EDGE4_BLOCKS ((N_EDGES / 4 + 255) / 256)      // 1563
#define ZERO_BLOCKS  ((N_NODES * 4 + 255) / 256)      // 1563 (int4 count)

typedef __attribute__((ext_vector_type(8))) short bf16x8_t;
typedef __attribute__((ext_vector_type(4))) float f32x4_t;
typedef __attribute__((ext_vector_type(2))) float f32x2_t;

// bf16 helpers (RNE)
__device__ __forceinline__ unsigned bf16rne(float x) {
  unsigned u = __float_as_uint(x);
  return (u + 0x7fffu + ((u >> 16) & 1u)) >> 16;
}
__device__ __forceinline__ unsigned packbf2(float lo, float hi) {
  return bf16rne(lo) | (bf16rne(hi) << 16);
}
// packed 2-wide f32 fma (v_pk_fma_f32 on CDNA)
__device__ __forceinline__ f32x2_t pkfma(f32x2_t a, f32x2_t b, f32x2_t c) {
  return __builtin_elementwise_fma(a, b, c);
}

// ============== prep: weight transpose (bf16) + cursor zeroing, fused ==============
__global__ __launch_bounds__(256)
void k_prep(const float* __restrict__ W1, const float* __restrict__ W2,
            unsigned* __restrict__ W1t32, unsigned* __restrict__ W2t32,
            int4* __restrict__ cursorPad4) {
  int t = threadIdx.x;
  if (blockIdx.x == 0) {
    int c = t;
    const float* wp = W1 + ((c >> 6) << 13) + (c & 63);
    unsigned* op = W1t32 + c * 64;
    for (int fp = 0; fp < 64; ++fp) {
      float lo = wp[(2 * fp) << 6];
      float hi = wp[(2 * fp + 1) << 6];
      op[fp] = packbf2(lo, hi);
    }
  } else if (blockIdx.x == 1) {
    int c = t & 63, fq = t >> 6;
    const float* wp = W2 + ((c >> 4) << 12) + (c & 15);
    unsigned* op = W2t32 + c * 128 + fq * 32;
    for (int fp = 0; fp < 32; ++fp) {
      int f0 = fq * 64 + 2 * fp;
      op[fp] = packbf2(wp[f0 << 4], wp[(f0 + 1) << 4]);
    }
  } else {
    int i = (blockIdx.x - 2) * 256 + t;
    if (i < N_NODES * 4) cursorPad4[i] = make_int4(0, 0, 0, 0);
  }
}

// ============================ CSR build ============================
// R6: 4 edges/thread — int4 coalesced dst load, FOUR independent return-atomics
// in flight before the single vmcnt wait, int4 rank store. 4x MLP per wave.
__global__ __launch_bounds__(256)
void k_count4(const int* __restrict__ dst, int* __restrict__ cursorPad,
              int* __restrict__ rank) {
  int v = blockIdx.x * blockDim.x + threadIdx.x;   // int4 index
  if (v < N_EDGES / 4) {
    int4 d = ((const int4*)dst)[v];
    int r0 = atomicAdd(&cursorPad[d.x << 4], 1);
    int r1 = atomicAdd(&cursorPad[d.y << 4], 1);
    int r2 = atomicAdd(&cursorPad[d.z << 4], 1);
    int r3 = atomicAdd(&cursorPad[d.w << 4], 1);
    ((int4*)rank)[v] = make_int4(r0, r1, r2, r3);
  }
}

__global__ __launch_bounds__(256)
void k_compact(const int* __restrict__ cursorPad, int* __restrict__ counts) {
  int i = blockIdx.x * blockDim.x + threadIdx.x;
  if (i < N_NODES_PAD) counts[i] = (i < N_NODES) ? cursorPad[i << 4] : 0;
}

__global__ __launch_bounds__(256)
void k_scanA(const int* __restrict__ counts, int* __restrict__ btot) {
  __shared__ int red[256];
  int t = threadIdx.x;
  const int4* cp = (const int4*)(counts + blockIdx.x * SCAN_CHUNK);
  int4 v = cp[t];
  red[t] = v.x + v.y + v.z + v.w;
  __syncthreads();
  for (int s = 128; s; s >>= 1) {
    if (t < s) red[t] += red[t + s];
    __syncthreads();
  }
  if (t == 0) btot[blockIdx.x] = red[0];
}

__global__ __launch_bounds__(128)
void k_scanB(const int* __restrict__ btot, int* __restrict__ bbase,
             int* __restrict__ offs) {
  __shared__ int part[128];
  int t = threadIdx.x;
  part[t] = (t < SCAN_NB) ? btot[t] : 0;
  __syncthreads();
  for (int o = 1; o < 128; o <<= 1) {
    int v = (t >= o) ? part[t - o] : 0;
    __syncthreads();
    part[t] += v;
    __syncthreads();
  }
  if (t < SCAN_NB) bbase[t] = (t == 0) ? 0 : part[t - 1];
  if (t == 0) offs[N_NODES] = N_EDGES;
}

__global__ __launch_bounds__(256)
void k_scanC(const int* __restrict__ counts, const int* __restrict__ bbase,
             int* __restrict__ offs) {
  __shared__ int part[256];
  int t = threadIdx.x;
  int gbase = blockIdx.x * SCAN_CHUNK;
  const int4* cp = (const int4*)(counts + gbase);
  int4 v = cp[t];
  int tot = v.x + v.y + v.z + v.w;
  part[t] = tot;
  __syncthreads();
  for (int o = 1; o < 256; o <<= 1) {
    int q = (t >= o) ? part[t - o] : 0;
    __syncthreads();
    part[t] += q;
    __syncthreads();
  }
  int run = bbase[blockIdx.x] + part[t] - tot;
  int i0 = gbase + t * 4;
  int o0 = run;
  int o1 = o0 + v.x;
  int o2 = o1 + v.y;
  int o3 = o2 + v.z;
  if (i0 + 0 < N_NODES) offs[i0 + 0] = o0;
  if (i0 + 1 < N_NODES) offs[i0 + 1] = o1;
  if (i0 + 2 < N_NODES) offs[i0 + 2] = o2;
  if (i0 + 3 < N_NODES) offs[i0 + 3] = o3;
}

// R6: 4 edges/thread scatter — int4 loads, 4 parallel offs gathers, 4 stores.
__global__ __launch_bounds__(256)
void k_scatter4(const int* __restrict__ src, const int* __restrict__ dst,
                const int* __restrict__ rank, const int* __restrict__ offs,
                int* __restrict__ csrsrc) {
  int v = blockIdx.x * blockDim.x + threadIdx.x;
  if (v < N_EDGES / 4) {
    int4 d = ((const int4*)dst)[v];
    int4 r = ((const int4*)rank)[v];
    int4 s = ((const int4*)src)[v];
    int o0 = offs[d.x], o1 = offs[d.y], o2 = offs[d.z], o3 = offs[d.w];
    csrsrc[o0 + r.x] = s.x;
    csrsrc[o1 + r.y] = s.y;
    csrsrc[o2 + r.z] = s.z;
    csrsrc[o3 + r.w] = s.w;
  }
}

// ============================ GEMM 1 (MFMA) + fused scores ============================
__global__ __launch_bounds__(256)
void k_gemm1(const float* __restrict__ h, const unsigned short* __restrict__ W1t,
             const float* __restrict__ bias, const float* __restrict__ a1,
             unsigned char* __restrict__ Wh8,
             float* __restrict__ sD, float* __restrict__ sS) {
  __shared__ float aLds[512];
  int t = threadIdx.x;
  aLds[t] = a1[t];
  aLds[t + 256] = a1[t + 256];
  __syncthreads();

  int wv = t >> 6;
  int lane = t & 63;
  int m = lane & 15;
  int q8 = (lane >> 4) * 8;
  int node = blockIdx.x * 64 + wv * 16 + m;
  int nclamp = node < N_NODES ? node : N_NODES - 1;

  f32x4_t acc[16] = {};
  const float* hp0 = h + (size_t)nclamp * IN_F + q8;
  #pragma unroll
  for (int ks = 0; ks < 4; ++ks) {
    int kk = ks * 32;
    float4 f0 = *(const float4*)(hp0 + kk);
    float4 f1 = *(const float4*)(hp0 + kk + 4);
    bf16x8_t bf;
    bf[0] = (short)bf16rne(f0.x); bf[1] = (short)bf16rne(f0.y);
    bf[2] = (short)bf16rne(f0.z); bf[3] = (short)bf16rne(f0.w);
    bf[4] = (short)bf16rne(f1.x); bf[5] = (short)bf16rne(f1.y);
    bf[6] = (short)bf16rne(f1.z); bf[7] = (short)bf16rne(f1.w);
    #pragma unroll
    for (int ct = 0; ct < 16; ++ct) {
      bf16x8_t af = *(const bf16x8_t*)(W1t + (ct * 16 + m) * IN_F + kk + q8);
      acc[ct] = __builtin_amdgcn_mfma_f32_16x16x32_bf16(af, bf, acc[ct], 0, 0, 0);
    }
  }
  if (node < N_NODES) {
    unsigned char* op = Wh8 + (size_t)node * D1;
    int quad4 = (lane >> 4) * 4;
    float pd[4] = {}, ps[4] = {};
    #pragma unroll
    for (int ct = 0; ct < 16; ++ct) {
      int c0 = ct * 16 + quad4;
      float4 bb = *(const float4*)(bias + c0);
      float v0 = acc[ct][0] + bb.x, v1 = acc[ct][1] + bb.y;
      float v2 = acc[ct][2] + bb.z, v3 = acc[ct][3] + bb.w;
      int hh = ct >> 2;
      const float* aD = &aLds[hh * 128 + (c0 & 63)];
      pd[hh] += v0 * aD[0] + v1 * aD[1] + v2 * aD[2] + v3 * aD[3];
      ps[hh] += v0 * aD[64] + v1 * aD[65] + v2 * aD[66] + v3 * aD[67];
      int pk = __builtin_amdgcn_cvt_pk_fp8_f32(v0, v1, 0, false);
      pk = __builtin_amdgcn_cvt_pk_fp8_f32(v2, v3, pk, true);
      *(unsigned*)(op + c0) = (unsigned)pk;
    }
    #pragma unroll
    for (int hh = 0; hh < 4; ++hh) {
      pd[hh] += __shfl_xor(pd[hh], 16); pd[hh] += __shfl_xor(pd[hh], 32);
      ps[hh] += __shfl_xor(ps[hh], 16); ps[hh] += __shfl_xor(ps[hh], 32);
    }
    if (lane < 16) {
      ((float4*)sD)[node] = make_float4(pd[0], pd[1], pd[2], pd[3]);
      ((float4*)sS)[node] = make_float4(ps[0], ps[1], ps[2], ps[3]);
    }
  }
}

// ============================ GEMM 2 (MFMA) + fused scores ============================
__global__ __launch_bounds__(256)
void k_gemm2(const unsigned short* __restrict__ h1b, const unsigned short* __restrict__ W2t,
             const float* __restrict__ bias, const float* __restrict__ a2,
             unsigned short* __restrict__ Whb2,
             float* __restrict__ sD, float* __restrict__ sS) {
  __shared__ float aLds[128];
  int t = threadIdx.x;
  if (t < 128) aLds[t] = a2[t];
  __syncthreads();

  int wv = t >> 6;
  int lane = t & 63;
  int m = lane & 15;
  int q8 = (lane >> 4) * 8;
  int node = blockIdx.x * 64 + wv * 16 + m;
  int nclamp = node < N_NODES ? node : N_NODES - 1;

  f32x4_t acc[4] = {};
  const unsigned short* hp0 = h1b + (size_t)nclamp * D1 + q8;
  #pragma unroll
  for (int ks = 0; ks < 8; ++ks) {
    int kk = ks * 32;
    bf16x8_t bf = *(const bf16x8_t*)(hp0 + kk);
    #pragma unroll
    for (int ct = 0; ct < 4; ++ct) {
      bf16x8_t af = *(const bf16x8_t*)(W2t + (ct * 16 + m) * D1 + kk + q8);
      acc[ct] = __builtin_amdgcn_mfma_f32_16x16x32_bf16(af, bf, acc[ct], 0, 0, 0);
    }
  }
  if (node < N_NODES) {
    unsigned short* op = Whb2 + (size_t)node * D2;
    int quad4 = (lane >> 4) * 4;
    float pd[4] = {}, ps[4] = {};
    #pragma unroll
    for (int ct = 0; ct < 4; ++ct) {
      int c0 = ct * 16 + quad4;
      float4 bb = *(const float4*)(bias + c0);
      float v0 = acc[ct][0] + bb.x, v1 = acc[ct][1] + bb.y;
      float v2 = acc[ct][2] + bb.z, v3 = acc[ct][3] + bb.w;
      const float* aD = &aLds[ct * 32 + (c0 & 15)];
      pd[ct] += v0 * aD[0] + v1 * aD[1] + v2 * aD[2] + v3 * aD[3];
      ps[ct] += v0 * aD[16] + v1 * aD[17] + v2 * aD[18] + v3 * aD[19];
      uint2 o;
      o.x = packbf2(v0, v1);
      o.y = packbf2(v2, v3);
      *(uint2*)(op + c0) = o;
    }
    #pragma unroll
    for (int hh = 0; hh < 4; ++hh) {
      pd[hh] += __shfl_xor(pd[hh], 16); pd[hh] += __shfl_xor(pd[hh], 32);
      ps[hh] += __shfl_xor(ps[hh], 16); ps[hh] += __shfl_xor(ps[hh], 32);
    }
    if (lane < 16) {
      ((float4*)sD)[node] = make_float4(pd[0], pd[1], pd[2], pd[3]);
      ((float4*)sS)[node] = make_float4(ps[0], ps[1], ps[2], ps[3]);
    }
  }
}

// ============================ layer-1 aggregate ============================
__device__ __forceinline__ float lrelu(float x) { return x > 0.f ? x : 0.2f * x; }
__device__ __forceinline__ float elu(float x)   { return x > 0.f ? x : expm1f(x); }

// R5 body (verified): persistent shell + QUAD gather streams + merged (off,w)
// LDS uint2 + v_pk_fma_f32 on cvt_pk outputs.
__global__ __launch_bounds__(256)
void k_agg1(const int* __restrict__ offs, const int* __restrict__ csrsrc,
            const float* __restrict__ sD, const float* __restrict__ sS,
            const float* __restrict__ ab,
            const unsigned char* __restrict__ Wh8, unsigned short* __restrict__ h1out) {
  __shared__ uint2 ewbuf[4][64 * 4];   // [wave][edge*4+hh] = {row byte off, w bits}
  int wv = threadIdx.x >> 6;
  int lane = threadIdx.x & 63;
  int g = lane >> 5;          // edge parity
  int l = lane & 31;          // 8B position within 256B row
  int hh = l >> 3;            // head of this lane's 8 feats
  unsigned lb = (unsigned)(l << 3);
  float ab0 = ab[0], ab1 = ab[1], ab2 = ab[2], ab3 = ab[3];
  const uint2* eb = ewbuf[wv];

  for (int wid = blockIdx.x * 4 + wv; wid < N_NODES; wid += AGG_WAVES) {
    f32x2_t acc[4] = {};      // 8 feats as packed pairs
    float z0 = 0.f, z1 = 0.f, z2 = 0.f, z3 = 0.f;
    int beg = offs[wid], end = offs[wid + 1];
    bool nonempty = end > beg;
    if (nonempty) {
      float4 dv = ((const float4*)sD)[wid];
      float db0 = dv.x + ab0, db1 = dv.y + ab1;
      float db2 = dv.z + ab2, db3 = dv.w + ab3;
      for (int cbeg = beg; cbeg < end; cbeg += 64) {
        int j = cbeg + lane;
        int cnt = end - cbeg; if (cnt > 64) cnt = 64;
        int sid = 0;
        float e0 = 0.f, e1 = 0.f, e2 = 0.f, e3 = 0.f;
        if (j < end) {
          sid = csrsrc[j];
          float4 sv = ((const float4*)sS)[sid];
          e0 = __expf(lrelu(db0 + sv.x));
          e1 = __expf(lrelu(db1 + sv.y));
          e2 = __expf(lrelu(db2 + sv.z));
          e3 = __expf(lrelu(db3 + sv.w));
          z0 += e0; z1 += e1; z2 += e2; z3 += e3;
        }
        unsigned ro = (unsigned)(sid << 8);   // fp8 row byte offset
        uint2* wp = &ewbuf[wv][lane * 4];
        wp[0] = make_uint2(ro, __float_as_uint(e0));
        wp[1] = make_uint2(ro, __float_as_uint(e1));
        wp[2] = make_uint2(ro, __float_as_uint(e2));
        wp[3] = make_uint2(ro, __float_as_uint(e3));
        int npairs = (cnt + 1) >> 1;
        int nh = (npairs + 3) >> 2;
        for (int u = 0; u < nh; ++u) {
          int i0 = 2 * u + g;
          int i1 = i0 + 2 * nh;
          int i2 = i0 + 4 * nh;            // max 8*nh-1 <= 63; pad slots zero-weight
          int i3 = i0 + 6 * nh;
          uint2 ew0 = eb[i0 * 4 + hh];
          uint2 ew1 = eb[i1 * 4 + hh];
          uint2 ew2 = eb[i2 * 4 + hh];
          uint2 ew3 = eb[i3 * 4 + hh];
          uint2 p0 = *(const uint2*)(Wh8 + (ew0.x + lb));
          uint2 p1 = *(const uint2*)(Wh8 + (ew1.x + lb));
          uint2 p2 = *(const uint2*)(Wh8 + (ew2.x + lb));
          uint2 p3 = *(const uint2*)(Wh8 + (ew3.x + lb));
          {
            float w = __uint_as_float(ew0.y); f32x2_t w2 = {w, w};
            acc[0] = pkfma(w2, __builtin_amdgcn_cvt_pk_f32_fp8(p0.x, false), acc[0]);
            acc[1] = pkfma(w2, __builtin_amdgcn_cvt_pk_f32_fp8(p0.x, true ), acc[1]);
            acc[2] = pkfma(w2, __builtin_amdgcn_cvt_pk_f32_fp8(p0.y, false), acc[2]);
            acc[3] = pkfma(w2, __builtin_amdgcn_cvt_pk_f32_fp8(p0.y, true ), acc[3]);
          }
          {
            float w = __uint_as_float(ew1.y); f32x2_t w2 = {w, w};
            acc[0] = pkfma(w2, __builtin_amdgcn_cvt_pk_f32_fp8(p1.x, false), acc[0]);
            acc[1] = pkfma(w2, __builtin_amdgcn_cvt_pk_f32_fp8(p1.x, true ), acc[1]);
            acc[2] = pkfma(w2, __builtin_amdgcn_cvt_pk_f32_fp8(p1.y, false), acc[2]);
            acc[3] = pkfma(w2, __builtin_amdgcn_cvt_pk_f32_fp8(p1.y, true ), acc[3]);
          }
          {
            float w = __uint_as_float(ew2.y); f32x2_t w2 = {w, w};
            acc[0] = pkfma(w2, __builtin_amdgcn_cvt_pk_f32_fp8(p2.x, false), acc[0]);
            acc[1] = pkfma(w2, __builtin_amdgcn_cvt_pk_f32_fp8(p2.x, true ), acc[1]);
            acc[2] = pkfma(w2, __builtin_amdgcn_cvt_pk_f32_fp8(p2.y, false), acc[2]);
            acc[3] = pkfma(w2, __builtin_amdgcn_cvt_pk_f32_fp8(p2.y, true ), acc[3]);
          }
          {
            float w = __uint_as_float(ew3.y); f32x2_t w2 = {w, w};
            acc[0] = pkfma(w2, __builtin_amdgcn_cvt_pk_f32_fp8(p3.x, false), acc[0]);
            acc[1] = pkfma(w2, __builtin_amdgcn_cvt_pk_f32_fp8(p3.x, true ), acc[1]);
            acc[2] = pkfma(w2, __builtin_amdgcn_cvt_pk_f32_fp8(p3.y, false), acc[2]);
            acc[3] = pkfma(w2, __builtin_amdgcn_cvt_pk_f32_fp8(p3.y, true ), acc[3]);
          }
        }
      }
      #pragma unroll
      for (int o = 32; o; o >>= 1) {
        z0 += __shfl_xor(z0, o);
        z1 += __shfl_xor(z1, o);
        z2 += __shfl_xor(z2, o);
        z3 += __shfl_xor(z3, o);
      }
    }
    #pragma unroll
    for (int i = 0; i < 4; ++i) {
      acc[i][0] += __shfl_xor(acc[i][0], 32);
      acc[i][1] += __shfl_xor(acc[i][1], 32);
    }
    float z = (hh == 0) ? z0 : (hh == 1) ? z1 : (hh == 2) ? z2 : z3;
    if (!nonempty) z = 1.f;
    float inv = 1.f / z;
    if (g == 0) {
      uint4 o;
      o.x = packbf2(elu(acc[0][0] * inv), elu(acc[0][1] * inv));
      o.y = packbf2(elu(acc[1][0] * inv), elu(acc[1][1] * inv));
      o.z = packbf2(elu(acc[2][0] * inv), elu(acc[2][1] * inv));
      o.w = packbf2(elu(acc[3][0] * inv), elu(acc[3][1] * inv));
      *(uint4*)(h1out + (size_t)wid * D1 + l * 8) = o;
    }
  }
}

// ============================ layer-2 aggregate + softmax + partial mean ====
// R5 body (verified): persistent shell + quad streams + merged (off,w) uint2 + pk_fma.
__global__ __launch_bounds__(256)
void k_agg2(const int* __restrict__ offs, const int* __restrict__ csrsrc,
            const float* __restrict__ sD, const float* __restrict__ sS,
            const float* __restrict__ ab,
            const unsigned short* __restrict__ Whb2, float* __restrict__ partials) {
  __shared__ uint2 ewbuf[4][64 * 4];
  __shared__ float red[4][16];
  int wv = threadIdx.x >> 6;
  int lane = threadIdx.x & 63;
  int g = lane >> 4;          // edge offset within group of 4
  int l = lane & 15;          // 8B position within 128B row
  int hh = l >> 2;            // head of this lane's 4 feats
  unsigned lb = (unsigned)(l << 3);
  float ab0 = ab[0], ab1 = ab[1], ab2 = ab[2], ab3 = ab[3];
  const uint2* eb = ewbuf[wv];
  float smacc[4] = {};        // running sum of softmax outputs over this wave's nodes

  for (int wid = blockIdx.x * 4 + wv; wid < N_NODES; wid += AGG_WAVES) {
    f32x2_t acc[2] = {};      // 4 feats as packed pairs
    float z0 = 0.f, z1 = 0.f, z2 = 0.f, z3 = 0.f;
    int beg = offs[wid], end = offs[wid + 1];
    bool nonempty = end > beg;
    if (nonempty) {
      float4 dv = ((const float4*)sD)[wid];
      float db0 = dv.x + ab0, db1 = dv.y + ab1;
      float db2 = dv.z + ab2, db3 = dv.w + ab3;
      for (int cbeg = beg; cbeg < end; cbeg += 64) {
        int j = cbeg + lane;
        int cnt = end - cbeg; if (cnt > 64) cnt = 64;
        int sid = 0;
        float e0 = 0.f, e1 = 0.f, e2 = 0.f, e3 = 0.f;
        if (j < end) {
          sid = csrsrc[j];
          float4 sv = ((const float4*)sS)[sid];
          e0 = __expf(lrelu(db0 + sv.x));
          e1 = __expf(lrelu(db1 + sv.y));
          e2 = __expf(lrelu(db2 + sv.z));
          e3 = __expf(lrelu(db3 + sv.w));
          z0 += e0; z1 += e1; z2 += e2; z3 += e3;
        }
        unsigned ro = (unsigned)(sid << 7);   // bf16 row byte offset (128B rows)
        uint2* wp = &ewbuf[wv][lane * 4];
        wp[0] = make_uint2(ro, __float_as_uint(e0));
        wp[1] = make_uint2(ro, __float_as_uint(e1));
        wp[2] = make_uint2(ro, __float_as_uint(e2));
        wp[3] = make_uint2(ro, __float_as_uint(e3));
        int ni = (cnt + 3) >> 2;
        int nq = (ni + 3) >> 2;
        for (int u = 0; u < nq; ++u) {
          int q0 = 4 * u + g;
          int q1 = q0 + 4 * nq;
          int q2 = q0 + 8 * nq;            // max 16*nq-1 <= 63; pad slots zero-weight
          int q3 = q0 + 12 * nq;
          uint2 ew0 = eb[q0 * 4 + hh];
          uint2 ew1 = eb[q1 * 4 + hh];
          uint2 ew2 = eb[q2 * 4 + hh];
          uint2 ew3 = eb[q3 * 4 + hh];
          const unsigned char* base = (const unsigned char*)Whb2;
          uint2 p0 = *(const uint2*)(base + (ew0.x + lb));
          uint2 p1 = *(const uint2*)(base + (ew1.x + lb));
          uint2 p2 = *(const uint2*)(base + (ew2.x + lb));
          uint2 p3 = *(const uint2*)(base + (ew3.x + lb));
          {
            float w = __uint_as_float(ew0.y); f32x2_t w2 = {w, w};
            f32x2_t dA, dB;
            dA[0] = __uint_as_float(p0.x << 16); dA[1] = __uint_as_float(p0.x & 0xffff0000u);
            dB[0] = __uint_as_float(p0.y << 16); dB[1] = __uint_as_float(p0.y & 0xffff0000u);
            acc[0] = pkfma(w2, dA, acc[0]);
            acc[1] = pkfma(w2, dB, acc[1]);
          }
          {
            float w = __uint_as_float(ew1.y); f32x2_t w2 = {w, w};
            f32x2_t dA, dB;
            dA[0] = __uint_as_float(p1.x << 16); dA[1] = __uint_as_float(p1.x & 0xffff0000u);
            dB[0] = __uint_as_float(p1.y << 16); dB[1] = __uint_as_float(p1.y & 0xffff0000u);
            acc[0] = pkfma(w2, dA, acc[0]);
            acc[1] = pkfma(w2, dB, acc[1]);
          }
          {
            float w = __uint_as_float(ew2.y); f32x2_t w2 = {w, w};
            f32x2_t dA, dB;
            dA[0] = __uint_as_float(p2.x << 16); dA[1] = __uint_as_float(p2.x & 0xffff0000u);
            dB[0] = __uint_as_float(p2.y << 16); dB[1] = __uint_as_float(p2.y & 0xffff0000u);
            acc[0] = pkfma(w2, dA, acc[0]);
            acc[1] = pkfma(w2, dB, acc[1]);
          }
          {
            float w = __uint_as_float(ew3.y); f32x2_t w2 = {w, w};
            f32x2_t dA, dB;
            dA[0] = __uint_as_float(p3.x << 16); dA[1] = __uint_as_float(p3.x & 0xffff0000u);
            dB[0] = __uint_as_float(p3.y << 16); dB[1] = __uint_as_float(p3.y & 0xffff0000u);
            acc[0] = pkfma(w2, dA, acc[0]);
            acc[1] = pkfma(w2, dB, acc[1]);
          }
        }
      }
      #pragma unroll
      for (int s = 32; s; s >>= 1) {
        z0 += __shfl_xor(z0, s);
        z1 += __shfl_xor(z1, s);
        z2 += __shfl_xor(z2, s);
        z3 += __shfl_xor(z3, s);
      }
    }
    #pragma unroll
    for (int i = 0; i < 2; ++i) {
      acc[i][0] += __shfl_xor(acc[i][0], 16);
      acc[i][1] += __shfl_xor(acc[i][1], 16);
      acc[i][0] += __shfl_xor(acc[i][0], 32);
      acc[i][1] += __shfl_xor(acc[i][1], 32);
    }
    float z = (hh == 0) ? z0 : (hh == 1) ? z1 : (hh == 2) ? z2 : z3;
    if (!nonempty) z = 1.f;
    float inv = 1.f / z;
    float val[4];
    val[0] = acc[0][0] * inv;
    val[1] = acc[0][1] * inv;
    val[2] = acc[1][0] * inv;
    val[3] = acc[1][1] * inv;
    #pragma unroll
    for (int i = 0; i < 4; ++i) {
      val[i] += __shfl_xor(val[i], 4);
      val[i] += __shfl_xor(val[i], 8);
      val[i] *= 0.25f;
    }
    float mx = fmaxf(fmaxf(val[0], val[1]), fmaxf(val[2], val[3]));
    mx = fmaxf(mx, __shfl_xor(mx, 1));
    mx = fmaxf(mx, __shfl_xor(mx, 2));
    float e[4];
    float ssum = 0.f;
    #pragma unroll
    for (int i = 0; i < 4; ++i) { e[i] = __expf(val[i] - mx); ssum += e[i]; }
    ssum += __shfl_xor(ssum, 1);
    ssum += __shfl_xor(ssum, 2);
    float rinv = 1.f / ssum;
    #pragma unroll
    for (int i = 0; i < 4; ++i) smacc[i] += e[i] * rinv;
  }

  // one block-level write: sum the 4 waves' running softmax sums
  if (g == 0 && l < 4) {
    #pragma unroll
    for (int i = 0; i < 4; ++i) red[wv][l * 4 + i] = smacc[i];
  }
  __syncthreads();
  if (threadIdx.x < 16) {
    partials[(size_t)blockIdx.x * 16 + threadIdx.x] =
        red[0][threadIdx.x] + red[1][threadIdx.x] +
        red[2][threadIdx.x] + red[3][threadIdx.x];
  }
}

// ============== hierarchical final reduce: 2048 -> 128 -> fc ==============
__global__ __launch_bounds__(256)
void k_reduce1(const float* __restrict__ partials, int nrows,
               float* __restrict__ out) {
  __shared__ float red[16][17];
  int t = threadIdx.x;
  int c = t & 15, rl = t >> 4;
  int per = (nrows + RB1 - 1) / RB1;
  int rbeg = blockIdx.x * per;
  int rend = rbeg + per; if (rend > nrows) rend = nrows;
  float s = 0.f;
  for (int r = rbeg + rl; r < rend; r += 16) s += partials[(size_t)r * 16 + c];
  red[rl][c] = s;
  __syncthreads();
  for (int st = 8; st; st >>= 1) {
    if (rl < st) red[rl][c] += red[rl + st][c];
    __syncthreads();
  }
  if (t < 16) out[(size_t)blockIdx.x * 16 + t] = red[0][t];
}

__global__ __launch_bounds__(256)
void k_final(const float* __restrict__ partials,
             const float* __restrict__ fcw, const float* __restrict__ fcb,
             float* __restrict__ out) {
  __shared__ float red[16][17];
  __shared__ float hg[16];
  int t = threadIdx.x;
  int c = t & 15, rl = t >> 4;
  float s = 0.f;
  for (int r = rl; r < RB1; r += 16) s += partials[(size_t)r * 16 + c];
  red[rl][c] = s;
  __syncthreads();
  for (int st = 8; st; st >>= 1) {
    if (rl < st) red[rl][c] += red[rl + st][c];
    __syncthreads();
  }
  if (t < 16) hg[t] = red[0][t] * (1.0f / N_NODES);
  __syncthreads();
  if (t < 16) {
    float acc = fcb[t];
    #pragma unroll
    for (int k = 0; k < 16; ++k) acc += hg[k] * fcw[t * 16 + k];
    out[t] = acc;
  }
}

// ============================ launcher ============================
extern "C" void kernel_launch(void* const* d_in, const int* in_sizes, int n_in,
                              void* d_out, int out_size, void* d_ws, size_t ws_size,
                              hipStream_t stream) {
  const float* h   = (const float*)d_in[0];
  const int*   src = (const int*)  d_in[1];
  const int*   dst = (const int*)  d_in[2];
  const float* W1  = (const float*)d_in[3];
  const float* b1  = (const float*)d_in[4];
  const float* a1  = (const float*)d_in[5];
  const float* ab1 = (const float*)d_in[6];
  const float* W2  = (const float*)d_in[7];
  const float* b2  = (const float*)d_in[8];
  const float* a2  = (const float*)d_in[9];
  const float* ab2 = (const float*)d_in[10];
  const float* fcw = (const float*)d_in[11];
  const float* fcb = (const float*)d_in[12];
  float* out = (float*)d_out;

  char* ws = (char*)d_ws;
  size_t off = 0;
  auto alloc = [&](size_t bytes) -> char* {
    char* p = ws + off;
    off += (bytes + 255) & ~(size_t)255;
    return p;
  };
  unsigned char*  Wh8  = (unsigned char*)alloc((size_t)N_NODES * D1);      // 25.6 MB fp8
  unsigned short* h1b  = (unsigned short*)alloc((size_t)N_NODES * D1 * 2); // 51.2 MB
  unsigned short* Whb2 = (unsigned short*)alloc((size_t)N_NODES * D2 * 2); // 12.8 MB
  unsigned short* W1t  = (unsigned short*)alloc((size_t)D1 * IN_F * 2);
  unsigned short* W2t  = (unsigned short*)alloc((size_t)D2 * D1 * 2);
  float* sD1 = (float*)alloc((size_t)N_NODES * 4 * 4);
  float* sS1 = (float*)alloc((size_t)N_NODES * 4 * 4);
  float* sD2 = (float*)alloc((size_t)N_NODES * 4 * 4);
  float* sS2 = (float*)alloc((size_t)N_NODES * 4 * 4);
  int* cursorPad = (int*)alloc((size_t)N_NODES * 16 * 4);   // 6.4 MB
  int* rank   = (int*)alloc((size_t)N_EDGES * 4);           // 6.4 MB
  int* counts = (int*)alloc((size_t)N_NODES_PAD * 4);
  int* offs   = (int*)alloc((size_t)(N_NODES + 1) * 4);
  int* csrsrc = (int*)alloc((size_t)N_EDGES * 4);
  int* btot   = (int*)alloc((size_t)SCAN_NB * 4);
  int* bbase  = (int*)alloc((size_t)SCAN_NB * 4);
  float* partials  = (float*)alloc((size_t)AGG_BLOCKS * 16 * 4);
  float* partials2 = (float*)alloc((size_t)RB1 * 16 * 4);

  // --- prep: weight transpose + cursor zero (fused) ---
  k_prep<<<2 + ZERO_BLOCKS, 256, 0, stream>>>(W1, W2, (unsigned*)W1t, (unsigned*)W2t,
                                              (int4*)cursorPad);

  // --- CSR count (4 edges/thread, 4 atomics in flight) ---
  k_count4<<<EDGE4_BLOCKS, 256, 0, stream>>>(dst, cursorPad, rank);

  // --- layer-1 GEMM (standalone, full MFMA occupancy) ---
  k_gemm1<<<GEMM1_BLOCKS, 256, 0, stream>>>(h, W1t, b1, a1, Wh8, sD1, sS1);

  // --- CSR finalize ---
  k_compact<<<(N_NODES_PAD + 255) / 256, 256, 0, stream>>>(cursorPad, counts);
  k_scanA<<<SCAN_NB, 256, 0, stream>>>(counts, btot);
  k_scanB<<<1, 128, 0, stream>>>(btot, bbase, offs);
  k_scanC<<<SCAN_NB, 256, 0, stream>>>(counts, bbase, offs);
  k_scatter4<<<EDGE4_BLOCKS, 256, 0, stream>>>(src, dst, rank, offs, csrsrc);

  // --- layer 1 aggregate ---
  k_agg1<<<AGG_BLOCKS, 256, 0, stream>>>(offs, csrsrc, sD1, sS1, ab1, Wh8, h1b);

  // --- layer 2 ---
  k_gemm2<<<GEMM1_BLOCKS, 256, 0, stream>>>(h1b, W2t, b2, a2, Whb2, sD2, sS2);
  k_agg2<<<AGG_BLOCKS, 256, 0, stream>>>(offs, csrsrc, sD2, sS2, ab2, Whb2, partials);

  // --- readout ---
  k_reduce1<<<RB1, 256, 0, stream>>>(partials, AGG_BLOCKS, partials2);
  k_final<<<1, 256, 0, stream>>>(partials2, fcw, fcb, out);
}

// Round 7
// 480.702 us; speedup vs baseline: 1.0454x; 1.0454x over previous
//
#include <hip/hip_runtime.h>
#include <math.h>

#define N_NODES  100000
#define N_EDGES  1600000
#define IN_F     128
#define HID      64
#define HEADS    4
#define NCLS     16
#define D1       (HEADS*HID)    // 256
#define D2       (HEADS*NCLS)   // 64

#define SCAN_CHUNK 1024
#define SCAN_NB    ((N_NODES + SCAN_CHUNK - 1) / SCAN_CHUNK)   // 98
#define N_NODES_PAD (SCAN_NB * SCAN_CHUNK)                     // 100352
#define RB1 128        // reduce-stage-1 blocks
#define AGG_BLOCKS 2048   // persistent agg grid: 256 CU x 8 blocks/CU
#define AGG_WAVES  (AGG_BLOCKS * 4)
#define GEMM1_BLOCKS ((N_NODES + 63) / 64)            // 1563
#define EDGE4_BLOCKS ((N_EDGES / 4 + 255) / 256)      // 1563
#define ZERO_BLOCKS  ((N_NODES * 4 + 255) / 256)      // 1563 (int4 count)

typedef __attribute__((ext_vector_type(8))) short bf16x8_t;
typedef __attribute__((ext_vector_type(4))) float f32x4_t;
typedef __attribute__((ext_vector_type(2))) float f32x2_t;

// bf16 helpers (RNE)
__device__ __forceinline__ unsigned bf16rne(float x) {
  unsigned u = __float_as_uint(x);
  return (u + 0x7fffu + ((u >> 16) & 1u)) >> 16;
}
__device__ __forceinline__ unsigned packbf2(float lo, float hi) {
  return bf16rne(lo) | (bf16rne(hi) << 16);
}
// packed 2-wide f32 fma (v_pk_fma_f32 on CDNA)
__device__ __forceinline__ f32x2_t pkfma(f32x2_t a, f32x2_t b, f32x2_t c) {
  return __builtin_elementwise_fma(a, b, c);
}

// ============== prep: weight transpose (bf16) + cursor zeroing, fused ==============
__global__ __launch_bounds__(256)
void k_prep(const float* __restrict__ W1, const float* __restrict__ W2,
            unsigned* __restrict__ W1t32, unsigned* __restrict__ W2t32,
            int4* __restrict__ cursorPad4) {
  int t = threadIdx.x;
  if (blockIdx.x == 0) {
    int c = t;
    const float* wp = W1 + ((c >> 6) << 13) + (c & 63);
    unsigned* op = W1t32 + c * 64;
    for (int fp = 0; fp < 64; ++fp) {
      float lo = wp[(2 * fp) << 6];
      float hi = wp[(2 * fp + 1) << 6];
      op[fp] = packbf2(lo, hi);
    }
  } else if (blockIdx.x == 1) {
    int c = t & 63, fq = t >> 6;
    const float* wp = W2 + ((c >> 4) << 12) + (c & 15);
    unsigned* op = W2t32 + c * 128 + fq * 32;
    for (int fp = 0; fp < 32; ++fp) {
      int f0 = fq * 64 + 2 * fp;
      op[fp] = packbf2(wp[f0 << 4], wp[(f0 + 1) << 4]);
    }
  } else {
    int i = (blockIdx.x - 2) * 256 + t;
    if (i < N_NODES * 4) cursorPad4[i] = make_int4(0, 0, 0, 0);
  }
}

// ============================ CSR build ============================
// 4 edges/thread — int4 coalesced dst load, FOUR independent return-atomics
// in flight before the single vmcnt wait, int4 rank store.
__global__ __launch_bounds__(256)
void k_count4(const int* __restrict__ dst, int* __restrict__ cursorPad,
              int* __restrict__ rank) {
  int v = blockIdx.x * blockDim.x + threadIdx.x;   // int4 index
  if (v < N_EDGES / 4) {
    int4 d = ((const int4*)dst)[v];
    int r0 = atomicAdd(&cursorPad[d.x << 4], 1);
    int r1 = atomicAdd(&cursorPad[d.y << 4], 1);
    int r2 = atomicAdd(&cursorPad[d.z << 4], 1);
    int r3 = atomicAdd(&cursorPad[d.w << 4], 1);
    ((int4*)rank)[v] = make_int4(r0, r1, r2, r3);
  }
}

// R7: compact fused into scanA — read cursorPad directly (strided), write
// counts (for scanC) + per-block totals. Saves one pass + one launch.
__global__ __launch_bounds__(256)
void k_scanAc(const int* __restrict__ cursorPad, int* __restrict__ counts,
              int* __restrict__ btot) {
  __shared__ int red[256];
  int t = threadIdx.x;
  int gbase = blockIdx.x * SCAN_CHUNK;
  int i0 = gbase + t * 4;
  int c0 = (i0 + 0 < N_NODES) ? cursorPad[(i0 + 0) << 4] : 0;
  int c1 = (i0 + 1 < N_NODES) ? cursorPad[(i0 + 1) << 4] : 0;
  int c2 = (i0 + 2 < N_NODES) ? cursorPad[(i0 + 2) << 4] : 0;
  int c3 = (i0 + 3 < N_NODES) ? cursorPad[(i0 + 3) << 4] : 0;
  ((int4*)counts)[(gbase >> 2) + t] = make_int4(c0, c1, c2, c3);
  red[t] = c0 + c1 + c2 + c3;
  __syncthreads();
  for (int s = 128; s; s >>= 1) {
    if (t < s) red[t] += red[t + s];
    __syncthreads();
  }
  if (t == 0) btot[blockIdx.x] = red[0];
}

__global__ __launch_bounds__(128)
void k_scanB(const int* __restrict__ btot, int* __restrict__ bbase,
             int* __restrict__ offs) {
  __shared__ int part[128];
  int t = threadIdx.x;
  part[t] = (t < SCAN_NB) ? btot[t] : 0;
  __syncthreads();
  for (int o = 1; o < 128; o <<= 1) {
    int v = (t >= o) ? part[t - o] : 0;
    __syncthreads();
    part[t] += v;
    __syncthreads();
  }
  if (t < SCAN_NB) bbase[t] = (t == 0) ? 0 : part[t - 1];
  if (t == 0) offs[N_NODES] = N_EDGES;
}

__global__ __launch_bounds__(256)
void k_scanC(const int* __restrict__ counts, const int* __restrict__ bbase,
             int* __restrict__ offs) {
  __shared__ int part[256];
  int t = threadIdx.x;
  int gbase = blockIdx.x * SCAN_CHUNK;
  const int4* cp = (const int4*)(counts + gbase);
  int4 v = cp[t];
  int tot = v.x + v.y + v.z + v.w;
  part[t] = tot;
  __syncthreads();
  for (int o = 1; o < 256; o <<= 1) {
    int q = (t >= o) ? part[t - o] : 0;
    __syncthreads();
    part[t] += q;
    __syncthreads();
  }
  int run = bbase[blockIdx.x] + part[t] - tot;
  int i0 = gbase + t * 4;
  int o0 = run;
  int o1 = o0 + v.x;
  int o2 = o1 + v.y;
  int o3 = o2 + v.z;
  if (i0 + 0 < N_NODES) offs[i0 + 0] = o0;
  if (i0 + 1 < N_NODES) offs[i0 + 1] = o1;
  if (i0 + 2 < N_NODES) offs[i0 + 2] = o2;
  if (i0 + 3 < N_NODES) offs[i0 + 3] = o3;
}

// 4 edges/thread scatter — int4 loads, 4 parallel offs gathers, 4 stores.
__global__ __launch_bounds__(256)
void k_scatter4(const int* __restrict__ src, const int* __restrict__ dst,
                const int* __restrict__ rank, const int* __restrict__ offs,
                int* __restrict__ csrsrc) {
  int v = blockIdx.x * blockDim.x + threadIdx.x;
  if (v < N_EDGES / 4) {
    int4 d = ((const int4*)dst)[v];
    int4 r = ((const int4*)rank)[v];
    int4 s = ((const int4*)src)[v];
    int o0 = offs[d.x], o1 = offs[d.y], o2 = offs[d.z], o3 = offs[d.w];
    csrsrc[o0 + r.x] = s.x;
    csrsrc[o1 + r.y] = s.y;
    csrsrc[o2 + r.z] = s.z;
    csrsrc[o3 + r.w] = s.w;
  }
}

// ============================ GEMM 1 (MFMA) + fused scores ============================
__global__ __launch_bounds__(256)
void k_gemm1(const float* __restrict__ h, const unsigned short* __restrict__ W1t,
             const float* __restrict__ bias, const float* __restrict__ a1,
             unsigned char* __restrict__ Wh8,
             float* __restrict__ sD, float* __restrict__ sS) {
  __shared__ float aLds[512];
  int t = threadIdx.x;
  aLds[t] = a1[t];
  aLds[t + 256] = a1[t + 256];
  __syncthreads();

  int wv = t >> 6;
  int lane = t & 63;
  int m = lane & 15;
  int q8 = (lane >> 4) * 8;
  int node = blockIdx.x * 64 + wv * 16 + m;
  int nclamp = node < N_NODES ? node : N_NODES - 1;

  f32x4_t acc[16] = {};
  const float* hp0 = h + (size_t)nclamp * IN_F + q8;
  #pragma unroll
  for (int ks = 0; ks < 4; ++ks) {
    int kk = ks * 32;
    float4 f0 = *(const float4*)(hp0 + kk);
    float4 f1 = *(const float4*)(hp0 + kk + 4);
    bf16x8_t bf;
    bf[0] = (short)bf16rne(f0.x); bf[1] = (short)bf16rne(f0.y);
    bf[2] = (short)bf16rne(f0.z); bf[3] = (short)bf16rne(f0.w);
    bf[4] = (short)bf16rne(f1.x); bf[5] = (short)bf16rne(f1.y);
    bf[6] = (short)bf16rne(f1.z); bf[7] = (short)bf16rne(f1.w);
    #pragma unroll
    for (int ct = 0; ct < 16; ++ct) {
      bf16x8_t af = *(const bf16x8_t*)(W1t + (ct * 16 + m) * IN_F + kk + q8);
      acc[ct] = __builtin_amdgcn_mfma_f32_16x16x32_bf16(af, bf, acc[ct], 0, 0, 0);
    }
  }
  if (node < N_NODES) {
    unsigned char* op = Wh8 + (size_t)node * D1;
    int quad4 = (lane >> 4) * 4;
    float pd[4] = {}, ps[4] = {};
    #pragma unroll
    for (int ct = 0; ct < 16; ++ct) {
      int c0 = ct * 16 + quad4;
      float4 bb = *(const float4*)(bias + c0);
      float v0 = acc[ct][0] + bb.x, v1 = acc[ct][1] + bb.y;
      float v2 = acc[ct][2] + bb.z, v3 = acc[ct][3] + bb.w;
      int hh = ct >> 2;
      const float* aD = &aLds[hh * 128 + (c0 & 63)];
      pd[hh] += v0 * aD[0] + v1 * aD[1] + v2 * aD[2] + v3 * aD[3];
      ps[hh] += v0 * aD[64] + v1 * aD[65] + v2 * aD[66] + v3 * aD[67];
      int pk = __builtin_amdgcn_cvt_pk_fp8_f32(v0, v1, 0, false);
      pk = __builtin_amdgcn_cvt_pk_fp8_f32(v2, v3, pk, true);
      *(unsigned*)(op + c0) = (unsigned)pk;
    }
    #pragma unroll
    for (int hh = 0; hh < 4; ++hh) {
      pd[hh] += __shfl_xor(pd[hh], 16); pd[hh] += __shfl_xor(pd[hh], 32);
      ps[hh] += __shfl_xor(ps[hh], 16); ps[hh] += __shfl_xor(ps[hh], 32);
    }
    if (lane < 16) {
      ((float4*)sD)[node] = make_float4(pd[0], pd[1], pd[2], pd[3]);
      ((float4*)sS)[node] = make_float4(ps[0], ps[1], ps[2], ps[3]);
    }
  }
}

// ============================ GEMM 2 (MFMA) + fused scores ============================
__global__ __launch_bounds__(256)
void k_gemm2(const unsigned short* __restrict__ h1b, const unsigned short* __restrict__ W2t,
             const float* __restrict__ bias, const float* __restrict__ a2,
             unsigned short* __restrict__ Whb2,
             float* __restrict__ sD, float* __restrict__ sS) {
  __shared__ float aLds[128];
  int t = threadIdx.x;
  if (t < 128) aLds[t] = a2[t];
  __syncthreads();

  int wv = t >> 6;
  int lane = t & 63;
  int m = lane & 15;
  int q8 = (lane >> 4) * 8;
  int node = blockIdx.x * 64 + wv * 16 + m;
  int nclamp = node < N_NODES ? node : N_NODES - 1;

  f32x4_t acc[4] = {};
  const unsigned short* hp0 = h1b + (size_t)nclamp * D1 + q8;
  #pragma unroll
  for (int ks = 0; ks < 8; ++ks) {
    int kk = ks * 32;
    bf16x8_t bf = *(const bf16x8_t*)(hp0 + kk);
    #pragma unroll
    for (int ct = 0; ct < 4; ++ct) {
      bf16x8_t af = *(const bf16x8_t*)(W2t + (ct * 16 + m) * D1 + kk + q8);
      acc[ct] = __builtin_amdgcn_mfma_f32_16x16x32_bf16(af, bf, acc[ct], 0, 0, 0);
    }
  }
  if (node < N_NODES) {
    unsigned short* op = Whb2 + (size_t)node * D2;
    int quad4 = (lane >> 4) * 4;
    float pd[4] = {}, ps[4] = {};
    #pragma unroll
    for (int ct = 0; ct < 4; ++ct) {
      int c0 = ct * 16 + quad4;
      float4 bb = *(const float4*)(bias + c0);
      float v0 = acc[ct][0] + bb.x, v1 = acc[ct][1] + bb.y;
      float v2 = acc[ct][2] + bb.z, v3 = acc[ct][3] + bb.w;
      const float* aD = &aLds[ct * 32 + (c0 & 15)];
      pd[ct] += v0 * aD[0] + v1 * aD[1] + v2 * aD[2] + v3 * aD[3];
      ps[ct] += v0 * aD[16] + v1 * aD[17] + v2 * aD[18] + v3 * aD[19];
      uint2 o;
      o.x = packbf2(v0, v1);
      o.y = packbf2(v2, v3);
      *(uint2*)(op + c0) = o;
    }
    #pragma unroll
    for (int hh = 0; hh < 4; ++hh) {
      pd[hh] += __shfl_xor(pd[hh], 16); pd[hh] += __shfl_xor(pd[hh], 32);
      ps[hh] += __shfl_xor(ps[hh], 16); ps[hh] += __shfl_xor(ps[hh], 32);
    }
    if (lane < 16) {
      ((float4*)sD)[node] = make_float4(pd[0], pd[1], pd[2], pd[3]);
      ((float4*)sS)[node] = make_float4(ps[0], ps[1], ps[2], ps[3]);
    }
  }
}

// ============================ layer-1 aggregate ============================
__device__ __forceinline__ float lrelu(float x) { return x > 0.f ? x : 0.2f * x; }
__device__ __forceinline__ float elu(float x)   { return x > 0.f ? x : expm1f(x); }

// R7: R4 dual-stream body (verified 98.5us, 0 bank conflicts) with ONE change:
// scalar fmaf -> v_pk_fma_f32 on the cvt_pk_f32_fp8 outputs (8 fma -> 4 pkfma).
// LDS layout identical to R4: float4 exbuf + int offbuf.
__global__ __launch_bounds__(256)
void k_agg1(const int* __restrict__ offs, const int* __restrict__ csrsrc,
            const float* __restrict__ sD, const float* __restrict__ sS,
            const float* __restrict__ ab,
            const unsigned char* __restrict__ Wh8, unsigned short* __restrict__ h1out) {
  __shared__ float exbuf[4][64 * 4];
  __shared__ int   offbuf[4][64];
  int wv = threadIdx.x >> 6;
  int lane = threadIdx.x & 63;
  int g = lane >> 5;          // edge parity
  int l = lane & 31;          // 8B position within 256B row
  int hh = l >> 3;            // head of this lane's 8 feats
  unsigned lb = (unsigned)(l << 3);
  float ab0 = ab[0], ab1 = ab[1], ab2 = ab[2], ab3 = ab[3];
  const float* eb = exbuf[wv];
  const int* ob = offbuf[wv];

  for (int wid = blockIdx.x * 4 + wv; wid < N_NODES; wid += AGG_WAVES) {
    f32x2_t acc[4] = {};      // 8 feats as packed pairs
    float z0 = 0.f, z1 = 0.f, z2 = 0.f, z3 = 0.f;
    int beg = offs[wid], end = offs[wid + 1];
    bool nonempty = end > beg;
    if (nonempty) {
      float4 dv = ((const float4*)sD)[wid];
      float db0 = dv.x + ab0, db1 = dv.y + ab1;
      float db2 = dv.z + ab2, db3 = dv.w + ab3;
      for (int cbeg = beg; cbeg < end; cbeg += 64) {
        int j = cbeg + lane;
        int cnt = end - cbeg; if (cnt > 64) cnt = 64;
        int sid = 0;
        float e0 = 0.f, e1 = 0.f, e2 = 0.f, e3 = 0.f;
        if (j < end) {
          sid = csrsrc[j];
          float4 sv = ((const float4*)sS)[sid];
          e0 = __expf(lrelu(db0 + sv.x));
          e1 = __expf(lrelu(db1 + sv.y));
          e2 = __expf(lrelu(db2 + sv.z));
          e3 = __expf(lrelu(db3 + sv.w));
          z0 += e0; z1 += e1; z2 += e2; z3 += e3;
        }
        offbuf[wv][lane] = sid << 8;   // fp8 row byte offset
        *(float4*)&exbuf[wv][lane * 4] = make_float4(e0, e1, e2, e3);
        int npairs = (cnt + 1) >> 1;
        int nh = (npairs + 1) >> 1;
        for (int u = 0; u < nh; ++u) {
          int iA = 2 * u + g;
          int iB = iA + 2 * nh;            // may exceed npairs -> zero slots
          float wA = eb[iA * 4 + hh];
          float wB = eb[iB * 4 + hh];
          unsigned vA = (unsigned)ob[iA] + lb;
          unsigned vB = (unsigned)ob[iB] + lb;
          uint2 pA = *(const uint2*)(Wh8 + vA);
          uint2 pB = *(const uint2*)(Wh8 + vB);
          f32x2_t wa2 = {wA, wA};
          acc[0] = pkfma(wa2, __builtin_amdgcn_cvt_pk_f32_fp8(pA.x, false), acc[0]);
          acc[1] = pkfma(wa2, __builtin_amdgcn_cvt_pk_f32_fp8(pA.x, true ), acc[1]);
          acc[2] = pkfma(wa2, __builtin_amdgcn_cvt_pk_f32_fp8(pA.y, false), acc[2]);
          acc[3] = pkfma(wa2, __builtin_amdgcn_cvt_pk_f32_fp8(pA.y, true ), acc[3]);
          f32x2_t wb2 = {wB, wB};
          acc[0] = pkfma(wb2, __builtin_amdgcn_cvt_pk_f32_fp8(pB.x, false), acc[0]);
          acc[1] = pkfma(wb2, __builtin_amdgcn_cvt_pk_f32_fp8(pB.x, true ), acc[1]);
          acc[2] = pkfma(wb2, __builtin_amdgcn_cvt_pk_f32_fp8(pB.y, false), acc[2]);
          acc[3] = pkfma(wb2, __builtin_amdgcn_cvt_pk_f32_fp8(pB.y, true ), acc[3]);
        }
      }
      #pragma unroll
      for (int o = 32; o; o >>= 1) {
        z0 += __shfl_xor(z0, o);
        z1 += __shfl_xor(z1, o);
        z2 += __shfl_xor(z2, o);
        z3 += __shfl_xor(z3, o);
      }
    }
    #pragma unroll
    for (int i = 0; i < 4; ++i) {
      acc[i][0] += __shfl_xor(acc[i][0], 32);
      acc[i][1] += __shfl_xor(acc[i][1], 32);
    }
    float z = (hh == 0) ? z0 : (hh == 1) ? z1 : (hh == 2) ? z2 : z3;
    if (!nonempty) z = 1.f;
    float inv = 1.f / z;
    if (g == 0) {
      uint4 o;
      o.x = packbf2(elu(acc[0][0] * inv), elu(acc[0][1] * inv));
      o.y = packbf2(elu(acc[1][0] * inv), elu(acc[1][1] * inv));
      o.z = packbf2(elu(acc[2][0] * inv), elu(acc[2][1] * inv));
      o.w = packbf2(elu(acc[3][0] * inv), elu(acc[3][1] * inv));
      *(uint4*)(h1out + (size_t)wid * D1 + l * 8) = o;
    }
  }
}

// ============================ layer-2 aggregate + softmax + partial mean ====
// R7: R4 dual-stream body + pk_fma (4 fma -> 2 pkfma). R4 LDS layout.
__global__ __launch_bounds__(256)
void k_agg2(const int* __restrict__ offs, const int* __restrict__ csrsrc,
            const float* __restrict__ sD, const float* __restrict__ sS,
            const float* __restrict__ ab,
            const unsigned short* __restrict__ Whb2, float* __restrict__ partials) {
  __shared__ float exbuf[4][64 * 4];
  __shared__ int   offbuf[4][64];
  __shared__ float red[4][16];
  int wv = threadIdx.x >> 6;
  int lane = threadIdx.x & 63;
  int g = lane >> 4;          // edge offset within group of 4
  int l = lane & 15;          // 8B position within 128B row
  int hh = l >> 2;            // head of this lane's 4 feats
  unsigned lb = (unsigned)(l << 3);
  float ab0 = ab[0], ab1 = ab[1], ab2 = ab[2], ab3 = ab[3];
  const float* eb = exbuf[wv];
  const int* ob = offbuf[wv];
  float smacc[4] = {};        // running sum of softmax outputs over this wave's nodes

  for (int wid = blockIdx.x * 4 + wv; wid < N_NODES; wid += AGG_WAVES) {
    f32x2_t acc[2] = {};      // 4 feats as packed pairs
    float z0 = 0.f, z1 = 0.f, z2 = 0.f, z3 = 0.f;
    int beg = offs[wid], end = offs[wid + 1];
    bool nonempty = end > beg;
    if (nonempty) {
      float4 dv = ((const float4*)sD)[wid];
      float db0 = dv.x + ab0, db1 = dv.y + ab1;
      float db2 = dv.z + ab2, db3 = dv.w + ab3;
      for (int cbeg = beg; cbeg < end; cbeg += 64) {
        int j = cbeg + lane;
        int cnt = end - cbeg; if (cnt > 64) cnt = 64;
        int sid = 0;
        float e0 = 0.f, e1 = 0.f, e2 = 0.f, e3 = 0.f;
        if (j < end) {
          sid = csrsrc[j];
          float4 sv = ((const float4*)sS)[sid];
          e0 = __expf(lrelu(db0 + sv.x));
          e1 = __expf(lrelu(db1 + sv.y));
          e2 = __expf(lrelu(db2 + sv.z));
          e3 = __expf(lrelu(db3 + sv.w));
          z0 += e0; z1 += e1; z2 += e2; z3 += e3;
        }
        offbuf[wv][lane] = sid << 7;
        *(float4*)&exbuf[wv][lane * 4] = make_float4(e0, e1, e2, e3);
        int ni = (cnt + 3) >> 2;
        int nh2 = (ni + 1) >> 1;
        for (int it = 0; it < nh2; ++it) {
          int qA = 4 * it + g;
          int qB = qA + 4 * nh2;           // may exceed cnt -> zero slots
          float wA = eb[qA * 4 + hh];
          float wB = eb[qB * 4 + hh];
          unsigned vA = (unsigned)ob[qA] + lb;
          unsigned vB = (unsigned)ob[qB] + lb;
          uint2 pA = *(const uint2*)((const unsigned char*)Whb2 + vA);
          uint2 pB = *(const uint2*)((const unsigned char*)Whb2 + vB);
          f32x2_t wa2 = {wA, wA};
          f32x2_t dA0, dA1;
          dA0[0] = __uint_as_float(pA.x << 16); dA0[1] = __uint_as_float(pA.x & 0xffff0000u);
          dA1[0] = __uint_as_float(pA.y << 16); dA1[1] = __uint_as_float(pA.y & 0xffff0000u);
          acc[0] = pkfma(wa2, dA0, acc[0]);
          acc[1] = pkfma(wa2, dA1, acc[1]);
          f32x2_t wb2 = {wB, wB};
          f32x2_t dB0, dB1;
          dB0[0] = __uint_as_float(pB.x << 16); dB0[1] = __uint_as_float(pB.x & 0xffff0000u);
          dB1[0] = __uint_as_float(pB.y << 16); dB1[1] = __uint_as_float(pB.y & 0xffff0000u);
          acc[0] = pkfma(wb2, dB0, acc[0]);
          acc[1] = pkfma(wb2, dB1, acc[1]);
        }
      }
      #pragma unroll
      for (int s = 32; s; s >>= 1) {
        z0 += __shfl_xor(z0, s);
        z1 += __shfl_xor(z1, s);
        z2 += __shfl_xor(z2, s);
        z3 += __shfl_xor(z3, s);
      }
    }
    #pragma unroll
    for (int i = 0; i < 2; ++i) {
      acc[i][0] += __shfl_xor(acc[i][0], 16);
      acc[i][1] += __shfl_xor(acc[i][1], 16);
      acc[i][0] += __shfl_xor(acc[i][0], 32);
      acc[i][1] += __shfl_xor(acc[i][1], 32);
    }
    float z = (hh == 0) ? z0 : (hh == 1) ? z1 : (hh == 2) ? z2 : z3;
    if (!nonempty) z = 1.f;
    float inv = 1.f / z;
    float val[4];
    val[0] = acc[0][0] * inv;
    val[1] = acc[0][1] * inv;
    val[2] = acc[1][0] * inv;
    val[3] = acc[1][1] * inv;
    #pragma unroll
    for (int i = 0; i < 4; ++i) {
      val[i] += __shfl_xor(val[i], 4);
      val[i] += __shfl_xor(val[i], 8);
      val[i] *= 0.25f;
    }
    float mx = fmaxf(fmaxf(val[0], val[1]), fmaxf(val[2], val[3]));
    mx = fmaxf(mx, __shfl_xor(mx, 1));
    mx = fmaxf(mx, __shfl_xor(mx, 2));
    float e[4];
    float ssum = 0.f;
    #pragma unroll
    for (int i = 0; i < 4; ++i) { e[i] = __expf(val[i] - mx); ssum += e[i]; }
    ssum += __shfl_xor(ssum, 1);
    ssum += __shfl_xor(ssum, 2);
    float rinv = 1.f / ssum;
    #pragma unroll
    for (int i = 0; i < 4; ++i) smacc[i] += e[i] * rinv;
  }

  // one block-level write: sum the 4 waves' running softmax sums
  if (g == 0 && l < 4) {
    #pragma unroll
    for (int i = 0; i < 4; ++i) red[wv][l * 4 + i] = smacc[i];
  }
  __syncthreads();
  if (threadIdx.x < 16) {
    partials[(size_t)blockIdx.x * 16 + threadIdx.x] =
        red[0][threadIdx.x] + red[1][threadIdx.x] +
        red[2][threadIdx.x] + red[3][threadIdx.x];
  }
}

// ============== hierarchical final reduce: 2048 -> 128 -> fc ==============
__global__ __launch_bounds__(256)
void k_reduce1(const float* __restrict__ partials, int nrows,
               float* __restrict__ out) {
  __shared__ float red[16][17];
  int t = threadIdx.x;
  int c = t & 15, rl = t >> 4;
  int per = (nrows + RB1 - 1) / RB1;
  int rbeg = blockIdx.x * per;
  int rend = rbeg + per; if (rend > nrows) rend = nrows;
  float s = 0.f;
  for (int r = rbeg + rl; r < rend; r += 16) s += partials[(size_t)r * 16 + c];
  red[rl][c] = s;
  __syncthreads();
  for (int st = 8; st; st >>= 1) {
    if (rl < st) red[rl][c] += red[rl + st][c];
    __syncthreads();
  }
  if (t < 16) out[(size_t)blockIdx.x * 16 + t] = red[0][t];
}

__global__ __launch_bounds__(256)
void k_final(const float* __restrict__ partials,
             const float* __restrict__ fcw, const float* __restrict__ fcb,
             float* __restrict__ out) {
  __shared__ float red[16][17];
  __shared__ float hg[16];
  int t = threadIdx.x;
  int c = t & 15, rl = t >> 4;
  float s = 0.f;
  for (int r = rl; r < RB1; r += 16) s += partials[(size_t)r * 16 + c];
  red[rl][c] = s;
  __syncthreads();
  for (int st = 8; st; st >>= 1) {
    if (rl < st) red[rl][c] += red[rl + st][c];
    __syncthreads();
  }
  if (t < 16) hg[t] = red[0][t] * (1.0f / N_NODES);
  __syncthreads();
  if (t < 16) {
    float acc = fcb[t];
    #pragma unroll
    for (int k = 0; k < 16; ++k) acc += hg[k] * fcw[t * 16 + k];
    out[t] = acc;
  }
}

// ============================ launcher ============================
extern "C" void kernel_launch(void* const* d_in, const int* in_sizes, int n_in,
                              void* d_out, int out_size, void* d_ws, size_t ws_size,
                              hipStream_t stream) {
  const float* h   = (const float*)d_in[0];
  const int*   src = (const int*)  d_in[1];
  const int*   dst = (const int*)  d_in[2];
  const float* W1  = (const float*)d_in[3];
  const float* b1  = (const float*)d_in[4];
  const float* a1  = (const float*)d_in[5];
  const float* ab1 = (const float*)d_in[6];
  const float* W2  = (const float*)d_in[7];
  const float* b2  = (const float*)d_in[8];
  const float* a2  = (const float*)d_in[9];
  const float* ab2 = (const float*)d_in[10];
  const float* fcw = (const float*)d_in[11];
  const float* fcb = (const float*)d_in[12];
  float* out = (float*)d_out;

  char* ws = (char*)d_ws;
  size_t off = 0;
  auto alloc = [&](size_t bytes) -> char* {
    char* p = ws + off;
    off += (bytes + 255) & ~(size_t)255;
    return p;
  };
  unsigned char*  Wh8  = (unsigned char*)alloc((size_t)N_NODES * D1);      // 25.6 MB fp8
  unsigned short* h1b  = (unsigned short*)alloc((size_t)N_NODES * D1 * 2); // 51.2 MB
  unsigned short* Whb2 = (unsigned short*)alloc((size_t)N_NODES * D2 * 2); // 12.8 MB
  unsigned short* W1t  = (unsigned short*)alloc((size_t)D1 * IN_F * 2);
  unsigned short* W2t  = (unsigned short*)alloc((size_t)D2 * D1 * 2);
  float* sD1 = (float*)alloc((size_t)N_NODES * 4 * 4);
  float* sS1 = (float*)alloc((size_t)N_NODES * 4 * 4);
  float* sD2 = (float*)alloc((size_t)N_NODES * 4 * 4);
  float* sS2 = (float*)alloc((size_t)N_NODES * 4 * 4);
  int* cursorPad = (int*)alloc((size_t)N_NODES * 16 * 4);   // 6.4 MB
  int* rank   = (int*)alloc((size_t)N_EDGES * 4);           // 6.4 MB
  int* counts = (int*)alloc((size_t)N_NODES_PAD * 4);
  int* offs   = (int*)alloc((size_t)(N_NODES + 1) * 4);
  int* csrsrc = (int*)alloc((size_t)N_EDGES * 4);
  int* btot   = (int*)alloc((size_t)SCAN_NB * 4);
  int* bbase  = (int*)alloc((size_t)SCAN_NB * 4);
  float* partials  = (float*)alloc((size_t)AGG_BLOCKS * 16 * 4);
  float* partials2 = (float*)alloc((size_t)RB1 * 16 * 4);

  // --- prep: weight transpose + cursor zero (fused) ---
  k_prep<<<2 + ZERO_BLOCKS, 256, 0, stream>>>(W1, W2, (unsigned*)W1t, (unsigned*)W2t,
                                              (int4*)cursorPad);

  // --- CSR count (4 edges/thread, 4 atomics in flight) ---
  k_count4<<<EDGE4_BLOCKS, 256, 0, stream>>>(dst, cursorPad, rank);

  // --- layer-1 GEMM (standalone, full MFMA occupancy) ---
  k_gemm1<<<GEMM1_BLOCKS, 256, 0, stream>>>(h, W1t, b1, a1, Wh8, sD1, sS1);

  // --- CSR finalize (compact fused into scanA) ---
  k_scanAc<<<SCAN_NB, 256, 0, stream>>>(cursorPad, counts, btot);
  k_scanB<<<1, 128, 0, stream>>>(btot, bbase, offs);
  k_scanC<<<SCAN_NB, 256, 0, stream>>>(counts, bbase, offs);
  k_scatter4<<<EDGE4_BLOCKS, 256, 0, stream>>>(src, dst, rank, offs, csrsrc);

  // --- layer 1 aggregate ---
  k_agg1<<<AGG_BLOCKS, 256, 0, stream>>>(offs, csrsrc, sD1, sS1, ab1, Wh8, h1b);

  // --- layer 2 ---
  k_gemm2<<<GEMM1_BLOCKS, 256, 0, stream>>>(h1b, W2t, b2, a2, Whb2, sD2, sS2);
  k_agg2<<<AGG_BLOCKS, 256, 0, stream>>>(offs, csrsrc, sD2, sS2, ab2, Whb2, partials);

  // --- readout ---
  k_reduce1<<<RB1, 256, 0, stream>>>(partials, AGG_BLOCKS, partials2);
  k_final<<<1, 256, 0, stream>>>(partials2, fcw, fcb, out);
}

// Round 8
// 409.434 us; speedup vs baseline: 1.2274x; 1.1741x over previous
//
#include <hip/hip_runtime.h>
#include <math.h>

#define N_NODES  100000
#define N_EDGES  1600000
#define IN_F     128
#define HID      64
#define HEADS    4
#define NCLS     16
#define D1       (HEADS*HID)    // 256
#define D2       (HEADS*NCLS)   // 64

#define RB1 128        // reduce-stage-1 blocks
#define AGG_BLOCKS 2048   // persistent agg grid: 256 CU x 8 blocks/CU
#define AGG_WAVES  (AGG_BLOCKS * 4)
#define GEMM1_BLOCKS ((N_NODES + 63) / 64)            // 1563

// bucket-sort CSR build
#define NBKT   ((N_NODES + 255) / 256)   // 391 coarse buckets (dst>>8)
#define BCAP   5120                      // region capacity (mean 4096, sigma~64)
#define BK_BLOCKS 256
#define BK_CHUNK  ((N_EDGES + BK_BLOCKS - 1) / BK_BLOCKS)   // 6250

typedef __attribute__((ext_vector_type(8))) short bf16x8_t;
typedef __attribute__((ext_vector_type(4))) float f32x4_t;
typedef __attribute__((ext_vector_type(2))) float f32x2_t;

// bf16 helpers (RNE)
__device__ __forceinline__ unsigned bf16rne(float x) {
  unsigned u = __float_as_uint(x);
  return (u + 0x7fffu + ((u >> 16) & 1u)) >> 16;
}
__device__ __forceinline__ unsigned packbf2(float lo, float hi) {
  return bf16rne(lo) | (bf16rne(hi) << 16);
}
// packed 2-wide f32 fma (v_pk_fma_f32 on CDNA)
__device__ __forceinline__ f32x2_t pkfma(f32x2_t a, f32x2_t b, f32x2_t c) {
  return __builtin_elementwise_fma(a, b, c);
}

// ============== prep: weight transpose (bf16) + bucket cursor zero ==============
__global__ __launch_bounds__(256)
void k_prep(const float* __restrict__ W1, const float* __restrict__ W2,
            unsigned* __restrict__ W1t32, unsigned* __restrict__ W2t32,
            int* __restrict__ cursor) {
  int t = threadIdx.x;
  if (blockIdx.x == 0) {
    int c = t;
    const float* wp = W1 + ((c >> 6) << 13) + (c & 63);
    unsigned* op = W1t32 + c * 64;
    for (int fp = 0; fp < 64; ++fp) {
      float lo = wp[(2 * fp) << 6];
      float hi = wp[(2 * fp + 1) << 6];
      op[fp] = packbf2(lo, hi);
    }
  } else if (blockIdx.x == 1) {
    int c = t & 63, fq = t >> 6;
    const float* wp = W2 + ((c >> 4) << 12) + (c & 15);
    unsigned* op = W2t32 + c * 128 + fq * 32;
    for (int fp = 0; fp < 32; ++fp) {
      int f0 = fq * 64 + 2 * fp;
      op[fp] = packbf2(wp[f0 << 4], wp[(f0 + 1) << 4]);
    }
  } else {
    for (int i = t; i <= NBKT; i += 256) cursor[i] = 0;
  }
}

// ============================ CSR build via 2-level bucket sort ============================
// Stage 1: coarse-bucket edges by dst>>8. Per block: LDS histogram over 391
// bins, ONE global return-atomic per non-empty bin (~100K total, replaces
// 1.6M per-edge device atomics), LDS rank, scatter packed (dstLow<<20|src)
// into fixed-capacity bucket regions.
__global__ __launch_bounds__(256)
void k_bucket(const int* __restrict__ src, const int* __restrict__ dst,
              int* __restrict__ cursor, unsigned* __restrict__ bucketed) {
  __shared__ int dstL[BK_CHUNK];
  __shared__ int srcL[BK_CHUNK];
  __shared__ int hist[NBKT];
  __shared__ int base[NBKT];
  __shared__ int cur[NBKT];
  int t = threadIdx.x;
  int e0 = blockIdx.x * BK_CHUNK;
  int e1 = e0 + BK_CHUNK; if (e1 > N_EDGES) e1 = N_EDGES;
  int n = e1 - e0;
  for (int i = t; i < NBKT; i += 256) { hist[i] = 0; cur[i] = 0; }
  __syncthreads();
  for (int i = t; i < n; i += 256) {
    int d = dst[e0 + i];
    int s = src[e0 + i];
    dstL[i] = d;
    srcL[i] = s;
    atomicAdd(&hist[d >> 8], 1);
  }
  __syncthreads();
  for (int i = t; i < NBKT; i += 256) {
    int hv = hist[i];
    base[i] = hv ? atomicAdd(&cursor[i], hv) : 0;
  }
  __syncthreads();
  for (int i = t; i < n; i += 256) {
    int d = dstL[i];
    int b = d >> 8;
    int r = atomicAdd(&cur[b], 1);
    unsigned q = (unsigned)(base[b] + r);
    if (q < BCAP)   // 16-sigma guard; memory safety only
      bucketed[(size_t)b * BCAP + q] = ((unsigned)(d & 255) << 20) | (unsigned)srcL[i];
  }
}

// Stage 1.5: scan 391 bucket totals -> global edge bases.
__global__ __launch_bounds__(512)
void k_bscan(const int* __restrict__ cursor, int* __restrict__ bbase,
             int* __restrict__ offs) {
  __shared__ int part[512];
  int t = threadIdx.x;
  part[t] = (t < NBKT) ? cursor[t] : 0;
  __syncthreads();
  for (int o = 1; o < 512; o <<= 1) {
    int v = (t >= o) ? part[t - o] : 0;
    __syncthreads();
    part[t] += v;
    __syncthreads();
  }
  if (t < NBKT) bbase[t] = (t == 0) ? 0 : part[t - 1];
  if (t == 0) offs[N_NODES] = N_EDGES;
}

// Stage 2: one block per bucket. LDS 256-bin count + scan -> offs for the
// bucket's 256 nodes; LDS rank -> csrsrc scatter. All per-edge atomics are LDS.
__global__ __launch_bounds__(256)
void k_b2csr(const unsigned* __restrict__ bucketed, const int* __restrict__ cursor,
             const int* __restrict__ bbase,
             int* __restrict__ offs, int* __restrict__ csrsrc) {
  __shared__ unsigned ed[BCAP];
  __shared__ int cnt[256];
  __shared__ int pfx[256];
  __shared__ int exc[256];
  __shared__ int cur[256];
  int b = blockIdx.x;
  int t = threadIdx.x;
  int n = cursor[b]; if (n > BCAP) n = BCAP;
  int gb = bbase[b];
  const unsigned* bp = bucketed + (size_t)b * BCAP;
  cnt[t] = 0;
  __syncthreads();
  for (int i = t; i < n; i += 256) {
    unsigned v = bp[i];
    ed[i] = v;
    atomicAdd(&cnt[v >> 20], 1);
  }
  __syncthreads();
  int x = cnt[t];
  pfx[t] = x;
  __syncthreads();
  for (int o = 1; o < 256; o <<= 1) {
    int v = (t >= o) ? pfx[t - o] : 0;
    __syncthreads();
    pfx[t] += v;
    __syncthreads();
  }
  int excl = pfx[t] - x;
  int node = b * 256 + t;
  if (node < N_NODES) offs[node] = gb + excl;
  exc[t] = excl;
  cur[t] = 0;
  __syncthreads();
  for (int i = t; i < n; i += 256) {
    unsigned v = ed[i];
    int d = v >> 20;
    int r = atomicAdd(&cur[d], 1);
    csrsrc[gb + exc[d] + r] = (int)(v & 0xFFFFFu);
  }
}

// ============================ GEMM 1 (MFMA) + fused scores ============================
__global__ __launch_bounds__(256)
void k_gemm1(const float* __restrict__ h, const unsigned short* __restrict__ W1t,
             const float* __restrict__ bias, const float* __restrict__ a1,
             unsigned char* __restrict__ Wh8,
             float* __restrict__ sD, float* __restrict__ sS) {
  __shared__ float aLds[512];
  int t = threadIdx.x;
  aLds[t] = a1[t];
  aLds[t + 256] = a1[t + 256];
  __syncthreads();

  int wv = t >> 6;
  int lane = t & 63;
  int m = lane & 15;
  int q8 = (lane >> 4) * 8;
  int node = blockIdx.x * 64 + wv * 16 + m;
  int nclamp = node < N_NODES ? node : N_NODES - 1;

  f32x4_t acc[16] = {};
  const float* hp0 = h + (size_t)nclamp * IN_F + q8;
  #pragma unroll
  for (int ks = 0; ks < 4; ++ks) {
    int kk = ks * 32;
    float4 f0 = *(const float4*)(hp0 + kk);
    float4 f1 = *(const float4*)(hp0 + kk + 4);
    bf16x8_t bf;
    bf[0] = (short)bf16rne(f0.x); bf[1] = (short)bf16rne(f0.y);
    bf[2] = (short)bf16rne(f0.z); bf[3] = (short)bf16rne(f0.w);
    bf[4] = (short)bf16rne(f1.x); bf[5] = (short)bf16rne(f1.y);
    bf[6] = (short)bf16rne(f1.z); bf[7] = (short)bf16rne(f1.w);
    #pragma unroll
    for (int ct = 0; ct < 16; ++ct) {
      bf16x8_t af = *(const bf16x8_t*)(W1t + (ct * 16 + m) * IN_F + kk + q8);
      acc[ct] = __builtin_amdgcn_mfma_f32_16x16x32_bf16(af, bf, acc[ct], 0, 0, 0);
    }
  }
  if (node < N_NODES) {
    unsigned char* op = Wh8 + (size_t)node * D1;
    int quad4 = (lane >> 4) * 4;
    float pd[4] = {}, ps[4] = {};
    #pragma unroll
    for (int ct = 0; ct < 16; ++ct) {
      int c0 = ct * 16 + quad4;
      float4 bb = *(const float4*)(bias + c0);
      float v0 = acc[ct][0] + bb.x, v1 = acc[ct][1] + bb.y;
      float v2 = acc[ct][2] + bb.z, v3 = acc[ct][3] + bb.w;
      int hh = ct >> 2;
      const float* aD = &aLds[hh * 128 + (c0 & 63)];
      pd[hh] += v0 * aD[0] + v1 * aD[1] + v2 * aD[2] + v3 * aD[3];
      ps[hh] += v0 * aD[64] + v1 * aD[65] + v2 * aD[66] + v3 * aD[67];
      int pk = __builtin_amdgcn_cvt_pk_fp8_f32(v0, v1, 0, false);
      pk = __builtin_amdgcn_cvt_pk_fp8_f32(v2, v3, pk, true);
      *(unsigned*)(op + c0) = (unsigned)pk;
    }
    #pragma unroll
    for (int hh = 0; hh < 4; ++hh) {
      pd[hh] += __shfl_xor(pd[hh], 16); pd[hh] += __shfl_xor(pd[hh], 32);
      ps[hh] += __shfl_xor(ps[hh], 16); ps[hh] += __shfl_xor(ps[hh], 32);
    }
    if (lane < 16) {
      ((float4*)sD)[node] = make_float4(pd[0], pd[1], pd[2], pd[3]);
      ((float4*)sS)[node] = make_float4(ps[0], ps[1], ps[2], ps[3]);
    }
  }
}

// ============================ GEMM 2 (MFMA) + fused scores ============================
__global__ __launch_bounds__(256)
void k_gemm2(const unsigned short* __restrict__ h1b, const unsigned short* __restrict__ W2t,
             const float* __restrict__ bias, const float* __restrict__ a2,
             unsigned short* __restrict__ Whb2,
             float* __restrict__ sD, float* __restrict__ sS) {
  __shared__ float aLds[128];
  int t = threadIdx.x;
  if (t < 128) aLds[t] = a2[t];
  __syncthreads();

  int wv = t >> 6;
  int lane = t & 63;
  int m = lane & 15;
  int q8 = (lane >> 4) * 8;
  int node = blockIdx.x * 64 + wv * 16 + m;
  int nclamp = node < N_NODES ? node : N_NODES - 1;

  f32x4_t acc[4] = {};
  const unsigned short* hp0 = h1b + (size_t)nclamp * D1 + q8;
  #pragma unroll
  for (int ks = 0; ks < 8; ++ks) {
    int kk = ks * 32;
    bf16x8_t bf = *(const bf16x8_t*)(hp0 + kk);
    #pragma unroll
    for (int ct = 0; ct < 4; ++ct) {
      bf16x8_t af = *(const bf16x8_t*)(W2t + (ct * 16 + m) * D1 + kk + q8);
      acc[ct] = __builtin_amdgcn_mfma_f32_16x16x32_bf16(af, bf, acc[ct], 0, 0, 0);
    }
  }
  if (node < N_NODES) {
    unsigned short* op = Whb2 + (size_t)node * D2;
    int quad4 = (lane >> 4) * 4;
    float pd[4] = {}, ps[4] = {};
    #pragma unroll
    for (int ct = 0; ct < 4; ++ct) {
      int c0 = ct * 16 + quad4;
      float4 bb = *(const float4*)(bias + c0);
      float v0 = acc[ct][0] + bb.x, v1 = acc[ct][1] + bb.y;
      float v2 = acc[ct][2] + bb.z, v3 = acc[ct][3] + bb.w;
      const float* aD = &aLds[ct * 32 + (c0 & 15)];
      pd[ct] += v0 * aD[0] + v1 * aD[1] + v2 * aD[2] + v3 * aD[3];
      ps[ct] += v0 * aD[16] + v1 * aD[17] + v2 * aD[18] + v3 * aD[19];
      uint2 o;
      o.x = packbf2(v0, v1);
      o.y = packbf2(v2, v3);
      *(uint2*)(op + c0) = o;
    }
    #pragma unroll
    for (int hh = 0; hh < 4; ++hh) {
      pd[hh] += __shfl_xor(pd[hh], 16); pd[hh] += __shfl_xor(pd[hh], 32);
      ps[hh] += __shfl_xor(ps[hh], 16); ps[hh] += __shfl_xor(ps[hh], 32);
    }
    if (lane < 16) {
      ((float4*)sD)[node] = make_float4(pd[0], pd[1], pd[2], pd[3]);
      ((float4*)sS)[node] = make_float4(ps[0], ps[1], ps[2], ps[3]);
    }
  }
}

// ============================ layer-1 aggregate ============================
__device__ __forceinline__ float lrelu(float x) { return x > 0.f ? x : 0.2f * x; }
__device__ __forceinline__ float elu(float x)   { return x > 0.f ? x : expm1f(x); }

// R7 body (verified ~97us, 0 bank conflicts): persistent shell + dual gather
// streams + pk_fma on cvt_pk outputs. float4 exbuf + int offbuf LDS layout.
__global__ __launch_bounds__(256)
void k_agg1(const int* __restrict__ offs, const int* __restrict__ csrsrc,
            const float* __restrict__ sD, const float* __restrict__ sS,
            const float* __restrict__ ab,
            const unsigned char* __restrict__ Wh8, unsigned short* __restrict__ h1out) {
  __shared__ float exbuf[4][64 * 4];
  __shared__ int   offbuf[4][64];
  int wv = threadIdx.x >> 6;
  int lane = threadIdx.x & 63;
  int g = lane >> 5;          // edge parity
  int l = lane & 31;          // 8B position within 256B row
  int hh = l >> 3;            // head of this lane's 8 feats
  unsigned lb = (unsigned)(l << 3);
  float ab0 = ab[0], ab1 = ab[1], ab2 = ab[2], ab3 = ab[3];
  const float* eb = exbuf[wv];
  const int* ob = offbuf[wv];

  for (int wid = blockIdx.x * 4 + wv; wid < N_NODES; wid += AGG_WAVES) {
    f32x2_t acc[4] = {};      // 8 feats as packed pairs
    float z0 = 0.f, z1 = 0.f, z2 = 0.f, z3 = 0.f;
    int beg = offs[wid], end = offs[wid + 1];
    bool nonempty = end > beg;
    if (nonempty) {
      float4 dv = ((const float4*)sD)[wid];
      float db0 = dv.x + ab0, db1 = dv.y + ab1;
      float db2 = dv.z + ab2, db3 = dv.w + ab3;
      for (int cbeg = beg; cbeg < end; cbeg += 64) {
        int j = cbeg + lane;
        int cnt = end - cbeg; if (cnt > 64) cnt = 64;
        int sid = 0;
        float e0 = 0.f, e1 = 0.f, e2 = 0.f, e3 = 0.f;
        if (j < end) {
          sid = csrsrc[j];
          float4 sv = ((const float4*)sS)[sid];
          e0 = __expf(lrelu(db0 + sv.x));
          e1 = __expf(lrelu(db1 + sv.y));
          e2 = __expf(lrelu(db2 + sv.z));
          e3 = __expf(lrelu(db3 + sv.w));
          z0 += e0; z1 += e1; z2 += e2; z3 += e3;
        }
        offbuf[wv][lane] = sid << 8;   // fp8 row byte offset
        *(float4*)&exbuf[wv][lane * 4] = make_float4(e0, e1, e2, e3);
        int npairs = (cnt + 1) >> 1;
        int nh = (npairs + 1) >> 1;
        for (int u = 0; u < nh; ++u) {
          int iA = 2 * u + g;
          int iB = iA + 2 * nh;            // may exceed npairs -> zero slots
          float wA = eb[iA * 4 + hh];
          float wB = eb[iB * 4 + hh];
          unsigned vA = (unsigned)ob[iA] + lb;
          unsigned vB = (unsigned)ob[iB] + lb;
          uint2 pA = *(const uint2*)(Wh8 + vA);
          uint2 pB = *(const uint2*)(Wh8 + vB);
          f32x2_t wa2 = {wA, wA};
          acc[0] = pkfma(wa2, __builtin_amdgcn_cvt_pk_f32_fp8(pA.x, false), acc[0]);
          acc[1] = pkfma(wa2, __builtin_amdgcn_cvt_pk_f32_fp8(pA.x, true ), acc[1]);
          acc[2] = pkfma(wa2, __builtin_amdgcn_cvt_pk_f32_fp8(pA.y, false), acc[2]);
          acc[3] = pkfma(wa2, __builtin_amdgcn_cvt_pk_f32_fp8(pA.y, true ), acc[3]);
          f32x2_t wb2 = {wB, wB};
          acc[0] = pkfma(wb2, __builtin_amdgcn_cvt_pk_f32_fp8(pB.x, false), acc[0]);
          acc[1] = pkfma(wb2, __builtin_amdgcn_cvt_pk_f32_fp8(pB.x, true ), acc[1]);
          acc[2] = pkfma(wb2, __builtin_amdgcn_cvt_pk_f32_fp8(pB.y, false), acc[2]);
          acc[3] = pkfma(wb2, __builtin_amdgcn_cvt_pk_f32_fp8(pB.y, true ), acc[3]);
        }
      }
      #pragma unroll
      for (int o = 32; o; o >>= 1) {
        z0 += __shfl_xor(z0, o);
        z1 += __shfl_xor(z1, o);
        z2 += __shfl_xor(z2, o);
        z3 += __shfl_xor(z3, o);
      }
    }
    #pragma unroll
    for (int i = 0; i < 4; ++i) {
      acc[i][0] += __shfl_xor(acc[i][0], 32);
      acc[i][1] += __shfl_xor(acc[i][1], 32);
    }
    float z = (hh == 0) ? z0 : (hh == 1) ? z1 : (hh == 2) ? z2 : z3;
    if (!nonempty) z = 1.f;
    float inv = 1.f / z;
    if (g == 0) {
      uint4 o;
      o.x = packbf2(elu(acc[0][0] * inv), elu(acc[0][1] * inv));
      o.y = packbf2(elu(acc[1][0] * inv), elu(acc[1][1] * inv));
      o.z = packbf2(elu(acc[2][0] * inv), elu(acc[2][1] * inv));
      o.w = packbf2(elu(acc[3][0] * inv), elu(acc[3][1] * inv));
      *(uint4*)(h1out + (size_t)wid * D1 + l * 8) = o;
    }
  }
}

// ============================ layer-2 aggregate + softmax + partial mean ====
// R7 body (verified): persistent shell + dual streams + pk_fma.
__global__ __launch_bounds__(256)
void k_agg2(const int* __restrict__ offs, const int* __restrict__ csrsrc,
            const float* __restrict__ sD, const float* __restrict__ sS,
            const float* __restrict__ ab,
            const unsigned short* __restrict__ Whb2, float* __restrict__ partials) {
  __shared__ float exbuf[4][64 * 4];
  __shared__ int   offbuf[4][64];
  __shared__ float red[4][16];
  int wv = threadIdx.x >> 6;
  int lane = threadIdx.x & 63;
  int g = lane >> 4;          // edge offset within group of 4
  int l = lane & 15;          // 8B position within 128B row
  int hh = l >> 2;            // head of this lane's 4 feats
  unsigned lb = (unsigned)(l << 3);
  float ab0 = ab[0], ab1 = ab[1], ab2 = ab[2], ab3 = ab[3];
  const float* eb = exbuf[wv];
  const int* ob = offbuf[wv];
  float smacc[4] = {};        // running sum of softmax outputs over this wave's nodes

  for (int wid = blockIdx.x * 4 + wv; wid < N_NODES; wid += AGG_WAVES) {
    f32x2_t acc[2] = {};      // 4 feats as packed pairs
    float z0 = 0.f, z1 = 0.f, z2 = 0.f, z3 = 0.f;
    int beg = offs[wid], end = offs[wid + 1];
    bool nonempty = end > beg;
    if (nonempty) {
      float4 dv = ((const float4*)sD)[wid];
      float db0 = dv.x + ab0, db1 = dv.y + ab1;
      float db2 = dv.z + ab2, db3 = dv.w + ab3;
      for (int cbeg = beg; cbeg < end; cbeg += 64) {
        int j = cbeg + lane;
        int cnt = end - cbeg; if (cnt > 64) cnt = 64;
        int sid = 0;
        float e0 = 0.f, e1 = 0.f, e2 = 0.f, e3 = 0.f;
        if (j < end) {
          sid = csrsrc[j];
          float4 sv = ((const float4*)sS)[sid];
          e0 = __expf(lrelu(db0 + sv.x));
          e1 = __expf(lrelu(db1 + sv.y));
          e2 = __expf(lrelu(db2 + sv.z));
          e3 = __expf(lrelu(db3 + sv.w));
          z0 += e0; z1 += e1; z2 += e2; z3 += e3;
        }
        offbuf[wv][lane] = sid << 7;
        *(float4*)&exbuf[wv][lane * 4] = make_float4(e0, e1, e2, e3);
        int ni = (cnt + 3) >> 2;
        int nh2 = (ni + 1) >> 1;
        for (int it = 0; it < nh2; ++it) {
          int qA = 4 * it + g;
          int qB = qA + 4 * nh2;           // may exceed cnt -> zero slots
          float wA = eb[qA * 4 + hh];
          float wB = eb[qB * 4 + hh];
          unsigned vA = (unsigned)ob[qA] + lb;
          unsigned vB = (unsigned)ob[qB] + lb;
          uint2 pA = *(const uint2*)((const unsigned char*)Whb2 + vA);
          uint2 pB = *(const uint2*)((const unsigned char*)Whb2 + vB);
          f32x2_t wa2 = {wA, wA};
          f32x2_t dA0, dA1;
          dA0[0] = __uint_as_float(pA.x << 16); dA0[1] = __uint_as_float(pA.x & 0xffff0000u);
          dA1[0] = __uint_as_float(pA.y << 16); dA1[1] = __uint_as_float(pA.y & 0xffff0000u);
          acc[0] = pkfma(wa2, dA0, acc[0]);
          acc[1] = pkfma(wa2, dA1, acc[1]);
          f32x2_t wb2 = {wB, wB};
          f32x2_t dB0, dB1;
          dB0[0] = __uint_as_float(pB.x << 16); dB0[1] = __uint_as_float(pB.x & 0xffff0000u);
          dB1[0] = __uint_as_float(pB.y << 16); dB1[1] = __uint_as_float(pB.y & 0xffff0000u);
          acc[0] = pkfma(wb2, dB0, acc[0]);
          acc[1] = pkfma(wb2, dB1, acc[1]);
        }
      }
      #pragma unroll
      for (int s = 32; s; s >>= 1) {
        z0 += __shfl_xor(z0, s);
        z1 += __shfl_xor(z1, s);
        z2 += __shfl_xor(z2, s);
        z3 += __shfl_xor(z3, s);
      }
    }
    #pragma unroll
    for (int i = 0; i < 2; ++i) {
      acc[i][0] += __shfl_xor(acc[i][0], 16);
      acc[i][1] += __shfl_xor(acc[i][1], 16);
      acc[i][0] += __shfl_xor(acc[i][0], 32);
      acc[i][1] += __shfl_xor(acc[i][1], 32);
    }
    float z = (hh == 0) ? z0 : (hh == 1) ? z1 : (hh == 2) ? z2 : z3;
    if (!nonempty) z = 1.f;
    float inv = 1.f / z;
    float val[4];
    val[0] = acc[0][0] * inv;
    val[1] = acc[0][1] * inv;
    val[2] = acc[1][0] * inv;
    val[3] = acc[1][1] * inv;
    #pragma unroll
    for (int i = 0; i < 4; ++i) {
      val[i] += __shfl_xor(val[i], 4);
      val[i] += __shfl_xor(val[i], 8);
      val[i] *= 0.25f;
    }
    float mx = fmaxf(fmaxf(val[0], val[1]), fmaxf(val[2], val[3]));
    mx = fmaxf(mx, __shfl_xor(mx, 1));
    mx = fmaxf(mx, __shfl_xor(mx, 2));
    float e[4];
    float ssum = 0.f;
    #pragma unroll
    for (int i = 0; i < 4; ++i) { e[i] = __expf(val[i] - mx); ssum += e[i]; }
    ssum += __shfl_xor(ssum, 1);
    ssum += __shfl_xor(ssum, 2);
    float rinv = 1.f / ssum;
    #pragma unroll
    for (int i = 0; i < 4; ++i) smacc[i] += e[i] * rinv;
  }

  // one block-level write: sum the 4 waves' running softmax sums
  if (g == 0 && l < 4) {
    #pragma unroll
    for (int i = 0; i < 4; ++i) red[wv][l * 4 + i] = smacc[i];
  }
  __syncthreads();
  if (threadIdx.x < 16) {
    partials[(size_t)blockIdx.x * 16 + threadIdx.x] =
        red[0][threadIdx.x] + red[1][threadIdx.x] +
        red[2][threadIdx.x] + red[3][threadIdx.x];
  }
}

// ============== hierarchical final reduce: 2048 -> 128 -> fc ==============
__global__ __launch_bounds__(256)
void k_reduce1(const float* __restrict__ partials, int nrows,
               float* __restrict__ out) {
  __shared__ float red[16][17];
  int t = threadIdx.x;
  int c = t & 15, rl = t >> 4;
  int per = (nrows + RB1 - 1) / RB1;
  int rbeg = blockIdx.x * per;
  int rend = rbeg + per; if (rend > nrows) rend = nrows;
  float s = 0.f;
  for (int r = rbeg + rl; r < rend; r += 16) s += partials[(size_t)r * 16 + c];
  red[rl][c] = s;
  __syncthreads();
  for (int st = 8; st; st >>= 1) {
    if (rl < st) red[rl][c] += red[rl + st][c];
    __syncthreads();
  }
  if (t < 16) out[(size_t)blockIdx.x * 16 + t] = red[0][t];
}

__global__ __launch_bounds__(256)
void k_final(const float* __restrict__ partials,
             const float* __restrict__ fcw, const float* __restrict__ fcb,
             float* __restrict__ out) {
  __shared__ float red[16][17];
  __shared__ float hg[16];
  int t = threadIdx.x;
  int c = t & 15, rl = t >> 4;
  float s = 0.f;
  for (int r = rl; r < RB1; r += 16) s += partials[(size_t)r * 16 + c];
  red[rl][c] = s;
  __syncthreads();
  for (int st = 8; st; st >>= 1) {
    if (rl < st) red[rl][c] += red[rl + st][c];
    __syncthreads();
  }
  if (t < 16) hg[t] = red[0][t] * (1.0f / N_NODES);
  __syncthreads();
  if (t < 16) {
    float acc = fcb[t];
    #pragma unroll
    for (int k = 0; k < 16; ++k) acc += hg[k] * fcw[t * 16 + k];
    out[t] = acc;
  }
}

// ============================ launcher ============================
extern "C" void kernel_launch(void* const* d_in, const int* in_sizes, int n_in,
                              void* d_out, int out_size, void* d_ws, size_t ws_size,
                              hipStream_t stream) {
  const float* h   = (const float*)d_in[0];
  const int*   src = (const int*)  d_in[1];
  const int*   dst = (const int*)  d_in[2];
  const float* W1  = (const float*)d_in[3];
  const float* b1  = (const float*)d_in[4];
  const float* a1  = (const float*)d_in[5];
  const float* ab1 = (const float*)d_in[6];
  const float* W2  = (const float*)d_in[7];
  const float* b2  = (const float*)d_in[8];
  const float* a2  = (const float*)d_in[9];
  const float* ab2 = (const float*)d_in[10];
  const float* fcw = (const float*)d_in[11];
  const float* fcb = (const float*)d_in[12];
  float* out = (float*)d_out;

  char* ws = (char*)d_ws;
  size_t off = 0;
  auto alloc = [&](size_t bytes) -> char* {
    char* p = ws + off;
    off += (bytes + 255) & ~(size_t)255;
    return p;
  };
  unsigned char*  Wh8  = (unsigned char*)alloc((size_t)N_NODES * D1);      // 25.6 MB fp8
  unsigned short* h1b  = (unsigned short*)alloc((size_t)N_NODES * D1 * 2); // 51.2 MB
  unsigned short* Whb2 = (unsigned short*)alloc((size_t)N_NODES * D2 * 2); // 12.8 MB
  unsigned short* W1t  = (unsigned short*)alloc((size_t)D1 * IN_F * 2);
  unsigned short* W2t  = (unsigned short*)alloc((size_t)D2 * D1 * 2);
  float* sD1 = (float*)alloc((size_t)N_NODES * 4 * 4);
  float* sS1 = (float*)alloc((size_t)N_NODES * 4 * 4);
  float* sD2 = (float*)alloc((size_t)N_NODES * 4 * 4);
  float* sS2 = (float*)alloc((size_t)N_NODES * 4 * 4);
  int* cursor   = (int*)alloc((size_t)(NBKT + 1) * 4);
  unsigned* bucketed = (unsigned*)alloc((size_t)NBKT * BCAP * 4);   // 8.0 MB
  int* bbase  = (int*)alloc((size_t)NBKT * 4);
  int* offs   = (int*)alloc((size_t)(N_NODES + 1) * 4);
  int* csrsrc = (int*)alloc((size_t)N_EDGES * 4);
  float* partials  = (float*)alloc((size_t)AGG_BLOCKS * 16 * 4);
  float* partials2 = (float*)alloc((size_t)RB1 * 16 * 4);

  // --- prep: weight transpose + bucket cursor zero ---
  k_prep<<<3, 256, 0, stream>>>(W1, W2, (unsigned*)W1t, (unsigned*)W2t, cursor);

  // --- CSR build via 2-level bucket sort (no per-edge device atomics) ---
  k_bucket<<<BK_BLOCKS, 256, 0, stream>>>(src, dst, cursor, bucketed);

  // --- layer-1 GEMM ---
  k_gemm1<<<GEMM1_BLOCKS, 256, 0, stream>>>(h, W1t, b1, a1, Wh8, sD1, sS1);

  // --- CSR finalize ---
  k_bscan<<<1, 512, 0, stream>>>(cursor, bbase, offs);
  k_b2csr<<<NBKT, 256, 0, stream>>>(bucketed, cursor, bbase, offs, csrsrc);

  // --- layer 1 aggregate ---
  k_agg1<<<AGG_BLOCKS, 256, 0, stream>>>(offs, csrsrc, sD1, sS1, ab1, Wh8, h1b);

  // --- layer 2 ---
  k_gemm2<<<GEMM1_BLOCKS, 256, 0, stream>>>(h1b, W2t, b2, a2, Whb2, sD2, sS2);
  k_agg2<<<AGG_BLOCKS, 256, 0, stream>>>(offs, csrsrc, sD2, sS2, ab2, Whb2, partials);

  // --- readout ---
  k_reduce1<<<RB1, 256, 0, stream>>>(partials, AGG_BLOCKS, partials2);
  k_final<<<1, 256, 0, stream>>>(partials2, fcw, fcb, out);
}